// Round 1
// baseline (359.917 us; speedup 1.0000x reference)
//
#include <hip/hip_runtime.h>
#include <hip/hip_bf16.h>

// GCN 2-layer forward on MI355X.
// Pipeline: deg count -> dinv -> scan (CSR rowstart) -> CSR fill ->
//           GEMM1(+dinv scale) -> pull-agg(+b1+relu) -> GEMM2(+dinv scale) -> pull-agg(+b2)

#define IN_C 128
#define HID_C 128
#define OUT_C 64

__global__ __launch_bounds__(256) void count_deg_kernel(
    const int* __restrict__ ei, int* __restrict__ deg, int E) {
  int e = blockIdx.x * blockDim.x + threadIdx.x;
  if (e >= E) return;
  int dst = ei[E + e];
  atomicAdd(&deg[dst], 1);
}

__global__ __launch_bounds__(256) void dinv_kernel(
    const int* __restrict__ deg, float* __restrict__ dinv, int n) {
  int i = blockIdx.x * blockDim.x + threadIdx.x;
  if (i >= n) return;
  // self-loop adds 1 to every node's degree -> deg+1 >= 1 always
  dinv[i] = rsqrtf((float)(deg[i] + 1));
}

// Single-block exclusive scan: each thread owns a contiguous chunk,
// wave-level shfl scans + one LDS pass for the 16 wave partials.
__global__ __launch_bounds__(1024) void scan_kernel(
    const int* __restrict__ deg, int* __restrict__ rowstart,
    int* __restrict__ cnt, int n) {
  const int T = 1024;
  int tid = threadIdx.x;
  int per = (n + T - 1) / T;
  int start = tid * per;
  int end = start + per;
  if (end > n) end = n;

  int local = 0;
  for (int i = start; i < end; ++i) local += deg[i];

  int lane = tid & 63;
  int wid = tid >> 6;
  int v = local;
  // inclusive scan within wave (64 lanes)
  #pragma unroll
  for (int off = 1; off < 64; off <<= 1) {
    int t = __shfl_up(v, off, 64);
    if (lane >= off) v += t;
  }
  __shared__ int wsum[16];
  if (lane == 63) wsum[wid] = v;
  __syncthreads();
  if (wid == 0) {
    int wv = (lane < 16) ? wsum[lane] : 0;
    #pragma unroll
    for (int off = 1; off < 16; off <<= 1) {
      int t = __shfl_up(wv, off, 64);
      if (lane >= off) wv += t;
    }
    if (lane < 16) wsum[lane] = wv;  // inclusive over waves
  }
  __syncthreads();
  int waveoff = (wid > 0) ? wsum[wid - 1] : 0;
  int excl = waveoff + v - local;  // exclusive prefix of this thread's chunk

  int run = excl;
  for (int i = start; i < end; ++i) {
    rowstart[i] = run;
    cnt[i] = run;
    run += deg[i];
  }
  if (tid == T - 1) rowstart[n] = run;  // chunks past n are empty -> run == total
}

__global__ __launch_bounds__(256) void fill_csr_kernel(
    const int* __restrict__ ei, int* __restrict__ cnt,
    int* __restrict__ csr_src, int E) {
  int e = blockIdx.x * blockDim.x + threadIdx.x;
  if (e >= E) return;
  int src = ei[e];
  int dst = ei[E + e];
  int pos = atomicAdd(&cnt[dst], 1);
  csr_src[pos] = src;
}

// H[row, col] = (sum_k X[row,k] * W[k,col]) * dinv[row]
// block = 256 threads, TM rows per block. X tile staged in LDS (16 KB),
// W streamed from global (64/32 KB, L2-resident, shared across blocks).
template <int CIN, int COUT, int TM>
__global__ __launch_bounds__(256) void gemm_scale_kernel(
    const float* __restrict__ X, const float* __restrict__ W,
    const float* __restrict__ dinv, float* __restrict__ H, int n) {
  constexpr int G = 256 / COUT;  // thread groups (row partitions)
  constexpr int R = TM / G;      // rows per thread
  __shared__ __align__(16) float Xs[TM * CIN];

  int tid = threadIdx.x;
  int col = tid % COUT;
  int g = tid / COUT;  // wave-uniform
  int row0 = blockIdx.x * TM;

  // load X tile (float4, coalesced, zero-pad past n)
  const float4* X4 = reinterpret_cast<const float4*>(X);
  float4* Xs4 = reinterpret_cast<float4*>(Xs);
  constexpr int XV = TM * CIN / 4;
  #pragma unroll
  for (int i4 = tid; i4 < XV; i4 += 256) {
    int r = row0 + i4 / (CIN / 4);
    float4 val = make_float4(0.f, 0.f, 0.f, 0.f);
    if (r < n) val = X4[(size_t)r * (CIN / 4) + (i4 % (CIN / 4))];
    Xs4[i4] = val;
  }
  __syncthreads();

  float acc[R];
  #pragma unroll
  for (int m = 0; m < R; ++m) acc[m] = 0.f;

  for (int k = 0; k < CIN; k += 4) {
    float w0 = W[(k + 0) * COUT + col];
    float w1 = W[(k + 1) * COUT + col];
    float w2 = W[(k + 2) * COUT + col];
    float w3 = W[(k + 3) * COUT + col];
    #pragma unroll
    for (int m = 0; m < R; ++m) {
      const float4 xv = *reinterpret_cast<const float4*>(&Xs[(g * R + m) * CIN + k]);
      acc[m] = fmaf(xv.x, w0, acc[m]);
      acc[m] = fmaf(xv.y, w1, acc[m]);
      acc[m] = fmaf(xv.z, w2, acc[m]);
      acc[m] = fmaf(xv.w, w3, acc[m]);
    }
  }

  #pragma unroll
  for (int m = 0; m < R; ++m) {
    int row = row0 + g * R + m;
    if (row < n) H[(size_t)row * COUT + col] = acc[m] * dinv[row];
  }
}

// out[node, :] = act( dinv[node] * (Hs[node,:] + sum_{src in CSR row} Hs[src,:]) + bias )
// Hs is already scaled by dinv[src]. One node per (C/4)-lane group, float4 lanes.
template <int C, bool RELU>
__global__ __launch_bounds__(256) void agg_kernel(
    const float* __restrict__ Hs, const int* __restrict__ rowstart,
    const int* __restrict__ csr_src, const float* __restrict__ dinv,
    const float* __restrict__ bias, float* __restrict__ out, int n) {
  constexpr int TPN = C / 4;        // threads per node
  constexpr int NPB = 256 / TPN;    // nodes per block
  int lane = threadIdx.x % TPN;
  int node = blockIdx.x * NPB + threadIdx.x / TPN;
  if (node >= n) return;

  const float4* H4 = reinterpret_cast<const float4*>(Hs);
  int s = rowstart[node];
  int e = rowstart[node + 1];

  float4 self = H4[(size_t)node * TPN + lane];  // self-loop term (hs already * dinv[node])
  float ax = self.x, ay = self.y, az = self.z, aw = self.w;
  float bx = 0.f, by = 0.f, bz = 0.f, bw = 0.f;

  int p = s;
  for (; p + 1 < e; p += 2) {
    int s0 = csr_src[p];
    int s1 = csr_src[p + 1];
    float4 v0 = H4[(size_t)s0 * TPN + lane];
    float4 v1 = H4[(size_t)s1 * TPN + lane];
    ax += v0.x; ay += v0.y; az += v0.z; aw += v0.w;
    bx += v1.x; by += v1.y; bz += v1.z; bw += v1.w;
  }
  if (p < e) {
    int s0 = csr_src[p];
    float4 v0 = H4[(size_t)s0 * TPN + lane];
    ax += v0.x; ay += v0.y; az += v0.z; aw += v0.w;
  }
  ax += bx; ay += by; az += bz; aw += bw;

  float di = dinv[node];
  float4 bv = reinterpret_cast<const float4*>(bias)[lane];
  float4 r;
  r.x = fmaf(ax, di, bv.x);
  r.y = fmaf(ay, di, bv.y);
  r.z = fmaf(az, di, bv.z);
  r.w = fmaf(aw, di, bv.w);
  if (RELU) {
    r.x = fmaxf(r.x, 0.f);
    r.y = fmaxf(r.y, 0.f);
    r.z = fmaxf(r.z, 0.f);
    r.w = fmaxf(r.w, 0.f);
  }
  reinterpret_cast<float4*>(out)[(size_t)node * TPN + lane] = r;
}

extern "C" void kernel_launch(void* const* d_in, const int* in_sizes, int n_in,
                              void* d_out, int out_size, void* d_ws, size_t ws_size,
                              hipStream_t stream) {
  const float* x  = (const float*)d_in[0];
  const int*   ei = (const int*)d_in[1];
  const float* W1 = (const float*)d_in[2];
  const float* b1 = (const float*)d_in[3];
  const float* W2 = (const float*)d_in[4];
  const float* b2 = (const float*)d_in[5];
  float* out = (float*)d_out;

  const int N = in_sizes[0] / IN_C;   // 50000
  const int E = in_sizes[1] / 2;      // 800000

  // workspace carve-out (256B aligned slabs)
  char* ws = (char*)d_ws;
  size_t off = 0;
  auto alloc = [&](size_t bytes) -> void* {
    void* p = ws + off;
    off += (bytes + 255) & ~(size_t)255;
    return p;
  };
  int*   deg      = (int*)  alloc((size_t)N * 4);
  float* dinv     = (float*)alloc((size_t)N * 4);
  int*   rowstart = (int*)  alloc((size_t)(N + 1) * 4);
  int*   cnt      = (int*)  alloc((size_t)N * 4);
  int*   csr_src  = (int*)  alloc((size_t)E * 4);
  float* hs       = (float*)alloc((size_t)N * HID_C * 4);  // reused for layer-2 (N*64)
  float* x2       = (float*)alloc((size_t)N * HID_C * 4);

  hipMemsetAsync(deg, 0, (size_t)N * 4, stream);
  count_deg_kernel<<<(E + 255) / 256, 256, 0, stream>>>(ei, deg, E);
  dinv_kernel<<<(N + 255) / 256, 256, 0, stream>>>(deg, dinv, N);
  scan_kernel<<<1, 1024, 0, stream>>>(deg, rowstart, cnt, N);
  fill_csr_kernel<<<(E + 255) / 256, 256, 0, stream>>>(ei, cnt, csr_src, E);

  // layer 1: hs = (x @ W1) * dinv ; x2 = relu(dinv * sum(hs) + b1)
  gemm_scale_kernel<IN_C, HID_C, 32><<<(N + 31) / 32, 256, 0, stream>>>(x, W1, dinv, hs, N);
  agg_kernel<HID_C, true><<<(N + 7) / 8, 256, 0, stream>>>(hs, rowstart, csr_src, dinv, b1, x2, N);

  // layer 2: hs2 = (x2 @ W2) * dinv ; out = dinv * sum(hs2) + b2
  gemm_scale_kernel<HID_C, OUT_C, 32><<<(N + 31) / 32, 256, 0, stream>>>(x2, W2, dinv, hs, N);
  agg_kernel<OUT_C, false><<<(N + 15) / 16, 256, 0, stream>>>(hs, rowstart, csr_src, dinv, b2, out, N);
}

// Round 2
// 257.602 us; speedup vs baseline: 1.3972x; 1.3972x over previous
//
#include <hip/hip_runtime.h>
#include <hip/hip_bf16.h>

// GCN 2-layer forward on MI355X.
// Pipeline: deg count -> 3-phase scan (CSR rowstart, fused dinv) -> CSR fill ->
//           GEMM1(+dinv scale) -> pull-agg(+b1+relu) -> GEMM2(+dinv scale) -> pull-agg(+b2)

#define IN_C 128
#define HID_C 128
#define OUT_C 64

__global__ __launch_bounds__(256) void count_deg_kernel(
    const int* __restrict__ ei, int* __restrict__ deg, int E) {
  int e = blockIdx.x * blockDim.x + threadIdx.x;
  if (e >= E) return;
  int dst = ei[E + e];
  atomicAdd(&deg[dst], 1);
}

// Phase A: per-block (256-elem chunk) sum of deg -> bsum[block]
__global__ __launch_bounds__(256) void scanA_kernel(
    const int* __restrict__ deg, int* __restrict__ bsum, int n) {
  int i = blockIdx.x * 256 + threadIdx.x;
  int v = (i < n) ? deg[i] : 0;
  #pragma unroll
  for (int off = 32; off > 0; off >>= 1) v += __shfl_down(v, off, 64);
  __shared__ int ws[4];
  int lane = threadIdx.x & 63, wid = threadIdx.x >> 6;
  if (lane == 0) ws[wid] = v;
  __syncthreads();
  if (threadIdx.x == 0) bsum[blockIdx.x] = ws[0] + ws[1] + ws[2] + ws[3];
}

// Phase B: single-block exclusive scan of bsum[0..G), G <= 1024, in place.
__global__ __launch_bounds__(1024) void scanB_kernel(int* __restrict__ bsum, int G) {
  int tid = threadIdx.x;
  int v = (tid < G) ? bsum[tid] : 0;
  int lane = tid & 63, wid = tid >> 6;
  int inc = v;
  #pragma unroll
  for (int off = 1; off < 64; off <<= 1) {
    int t = __shfl_up(inc, off, 64);
    if (lane >= off) inc += t;
  }
  __shared__ int wsum[16];
  if (lane == 63) wsum[wid] = inc;
  __syncthreads();
  if (wid == 0) {
    int wv = (lane < 16) ? wsum[lane] : 0;
    #pragma unroll
    for (int off = 1; off < 16; off <<= 1) {
      int t = __shfl_up(wv, off, 64);
      if (lane >= off) wv += t;
    }
    if (lane < 16) wsum[lane] = wv;  // inclusive over waves
  }
  __syncthreads();
  int excl = (wid > 0 ? wsum[wid - 1] : 0) + inc - v;
  if (tid < G) bsum[tid] = excl;
}

// Phase C: per-block local exclusive scan + block offset -> rowstart/cnt; fused dinv.
__global__ __launch_bounds__(256) void scanC_kernel(
    const int* __restrict__ deg, const int* __restrict__ boff,
    int* __restrict__ rowstart, int* __restrict__ cnt,
    float* __restrict__ dinv, int n) {
  int tid = threadIdx.x;
  int i = blockIdx.x * 256 + tid;
  int v = (i < n) ? deg[i] : 0;
  int lane = tid & 63, wid = tid >> 6;
  int inc = v;
  #pragma unroll
  for (int off = 1; off < 64; off <<= 1) {
    int t = __shfl_up(inc, off, 64);
    if (lane >= off) inc += t;
  }
  __shared__ int wsum[4];
  if (lane == 63) wsum[wid] = inc;
  __syncthreads();
  if (tid == 0) {
    int a = wsum[0], b = wsum[1], c = wsum[2];
    wsum[0] = 0; wsum[1] = a; wsum[2] = a + b; wsum[3] = a + b + c;
  }
  __syncthreads();
  int excl = boff[blockIdx.x] + wsum[wid] + inc - v;
  if (i < n) {
    rowstart[i] = excl;
    cnt[i] = excl;
    dinv[i] = rsqrtf((float)(v + 1));  // self-loop adds 1
    if (i == n - 1) rowstart[n] = excl + v;
  }
}

__global__ __launch_bounds__(256) void fill_csr_kernel(
    const int* __restrict__ ei, int* __restrict__ cnt,
    int* __restrict__ csr_src, int E) {
  int e = blockIdx.x * blockDim.x + threadIdx.x;
  if (e >= E) return;
  int src = ei[e];
  int dst = ei[E + e];
  int pos = atomicAdd(&cnt[dst], 1);
  csr_src[pos] = src;
}

// H[row, col] = (sum_k X[row,k] * W[k,col]) * dinv[row]
template <int CIN, int COUT, int TM>
__global__ __launch_bounds__(256) void gemm_scale_kernel(
    const float* __restrict__ X, const float* __restrict__ W,
    const float* __restrict__ dinv, float* __restrict__ H, int n) {
  constexpr int G = 256 / COUT;  // thread groups (row partitions)
  constexpr int R = TM / G;      // rows per thread
  __shared__ __align__(16) float Xs[TM * CIN];

  int tid = threadIdx.x;
  int col = tid % COUT;
  int g = tid / COUT;  // wave-uniform
  int row0 = blockIdx.x * TM;

  const float4* X4 = reinterpret_cast<const float4*>(X);
  float4* Xs4 = reinterpret_cast<float4*>(Xs);
  constexpr int XV = TM * CIN / 4;
  #pragma unroll
  for (int i4 = tid; i4 < XV; i4 += 256) {
    int r = row0 + i4 / (CIN / 4);
    float4 val = make_float4(0.f, 0.f, 0.f, 0.f);
    if (r < n) val = X4[(size_t)r * (CIN / 4) + (i4 % (CIN / 4))];
    Xs4[i4] = val;
  }
  __syncthreads();

  float acc[R];
  #pragma unroll
  for (int m = 0; m < R; ++m) acc[m] = 0.f;

  for (int k = 0; k < CIN; k += 4) {
    float w0 = W[(k + 0) * COUT + col];
    float w1 = W[(k + 1) * COUT + col];
    float w2 = W[(k + 2) * COUT + col];
    float w3 = W[(k + 3) * COUT + col];
    #pragma unroll
    for (int m = 0; m < R; ++m) {
      const float4 xv = *reinterpret_cast<const float4*>(&Xs[(g * R + m) * CIN + k]);
      acc[m] = fmaf(xv.x, w0, acc[m]);
      acc[m] = fmaf(xv.y, w1, acc[m]);
      acc[m] = fmaf(xv.z, w2, acc[m]);
      acc[m] = fmaf(xv.w, w3, acc[m]);
    }
  }

  #pragma unroll
  for (int m = 0; m < R; ++m) {
    int row = row0 + g * R + m;
    if (row < n) H[(size_t)row * COUT + col] = acc[m] * dinv[row];
  }
}

// out[node, :] = act( dinv[node] * (Hs[node,:] + sum_{src in CSR row} Hs[src,:]) + bias )
template <int C, bool RELU>
__global__ __launch_bounds__(256) void agg_kernel(
    const float* __restrict__ Hs, const int* __restrict__ rowstart,
    const int* __restrict__ csr_src, const float* __restrict__ dinv,
    const float* __restrict__ bias, float* __restrict__ out, int n) {
  constexpr int TPN = C / 4;        // threads per node
  constexpr int NPB = 256 / TPN;    // nodes per block
  int lane = threadIdx.x % TPN;
  int node = blockIdx.x * NPB + threadIdx.x / TPN;
  if (node >= n) return;

  const float4* H4 = reinterpret_cast<const float4*>(Hs);
  int s = rowstart[node];
  int e = rowstart[node + 1];

  float4 self = H4[(size_t)node * TPN + lane];
  float ax = self.x, ay = self.y, az = self.z, aw = self.w;
  float bx = 0.f, by = 0.f, bz = 0.f, bw = 0.f;

  int p = s;
  for (; p + 1 < e; p += 2) {
    int s0 = csr_src[p];
    int s1 = csr_src[p + 1];
    float4 v0 = H4[(size_t)s0 * TPN + lane];
    float4 v1 = H4[(size_t)s1 * TPN + lane];
    ax += v0.x; ay += v0.y; az += v0.z; aw += v0.w;
    bx += v1.x; by += v1.y; bz += v1.z; bw += v1.w;
  }
  if (p < e) {
    int s0 = csr_src[p];
    float4 v0 = H4[(size_t)s0 * TPN + lane];
    ax += v0.x; ay += v0.y; az += v0.z; aw += v0.w;
  }
  ax += bx; ay += by; az += bz; aw += bw;

  float di = dinv[node];
  float4 bv = reinterpret_cast<const float4*>(bias)[lane];
  float4 r;
  r.x = fmaf(ax, di, bv.x);
  r.y = fmaf(ay, di, bv.y);
  r.z = fmaf(az, di, bv.z);
  r.w = fmaf(aw, di, bv.w);
  if (RELU) {
    r.x = fmaxf(r.x, 0.f);
    r.y = fmaxf(r.y, 0.f);
    r.z = fmaxf(r.z, 0.f);
    r.w = fmaxf(r.w, 0.f);
  }
  reinterpret_cast<float4*>(out)[(size_t)node * TPN + lane] = r;
}

extern "C" void kernel_launch(void* const* d_in, const int* in_sizes, int n_in,
                              void* d_out, int out_size, void* d_ws, size_t ws_size,
                              hipStream_t stream) {
  const float* x  = (const float*)d_in[0];
  const int*   ei = (const int*)d_in[1];
  const float* W1 = (const float*)d_in[2];
  const float* b1 = (const float*)d_in[3];
  const float* W2 = (const float*)d_in[4];
  const float* b2 = (const float*)d_in[5];
  float* out = (float*)d_out;

  const int N = in_sizes[0] / IN_C;   // 50000
  const int E = in_sizes[1] / 2;      // 800000
  const int G = (N + 255) / 256;      // scan blocks (196)

  char* ws = (char*)d_ws;
  size_t off = 0;
  auto alloc = [&](size_t bytes) -> void* {
    void* p = ws + off;
    off += (bytes + 255) & ~(size_t)255;
    return p;
  };
  int*   deg      = (int*)  alloc((size_t)N * 4);
  float* dinv     = (float*)alloc((size_t)N * 4);
  int*   rowstart = (int*)  alloc((size_t)(N + 1) * 4);
  int*   cnt      = (int*)  alloc((size_t)N * 4);
  int*   bsum     = (int*)  alloc((size_t)G * 4);
  int*   csr_src  = (int*)  alloc((size_t)E * 4);
  float* hs       = (float*)alloc((size_t)N * HID_C * 4);
  float* x2       = (float*)alloc((size_t)N * HID_C * 4);

  hipMemsetAsync(deg, 0, (size_t)N * 4, stream);
  count_deg_kernel<<<(E + 255) / 256, 256, 0, stream>>>(ei, deg, E);
  scanA_kernel<<<G, 256, 0, stream>>>(deg, bsum, N);
  scanB_kernel<<<1, 1024, 0, stream>>>(bsum, G);
  scanC_kernel<<<G, 256, 0, stream>>>(deg, bsum, rowstart, cnt, dinv, N);
  fill_csr_kernel<<<(E + 255) / 256, 256, 0, stream>>>(ei, cnt, csr_src, E);

  gemm_scale_kernel<IN_C, HID_C, 32><<<(N + 31) / 32, 256, 0, stream>>>(x, W1, dinv, hs, N);
  agg_kernel<HID_C, true><<<(N + 7) / 8, 256, 0, stream>>>(hs, rowstart, csr_src, dinv, b1, x2, N);

  gemm_scale_kernel<HID_C, OUT_C, 32><<<(N + 31) / 32, 256, 0, stream>>>(x2, W2, dinv, hs, N);
  agg_kernel<OUT_C, false><<<(N + 15) / 16, 256, 0, stream>>>(hs, rowstart, csr_src, dinv, b2, out, N);
}

// Round 3
// 253.276 us; speedup vs baseline: 1.4210x; 1.0171x over previous
//
#include <hip/hip_runtime.h>
#include <hip/hip_bf16.h>

// GCN 2-layer forward on MI355X.
// Pipeline: deg count -> 3-phase scan (CSR rowstart, fused dinv) -> CSR fill ->
//           GEMM1(+dinv scale) -> pull-agg(+b1+relu) -> GEMM2(+dinv scale) -> pull-agg(+b2)

#define IN_C 128
#define HID_C 128
#define OUT_C 64

__global__ __launch_bounds__(256) void count_deg_kernel(
    const int* __restrict__ ei, int* __restrict__ deg, int E) {
  int e = blockIdx.x * blockDim.x + threadIdx.x;
  if (e >= E) return;
  int dst = ei[E + e];
  atomicAdd(&deg[dst], 1);
}

// Phase A: per-block (256-elem chunk) sum of deg -> bsum[block]
__global__ __launch_bounds__(256) void scanA_kernel(
    const int* __restrict__ deg, int* __restrict__ bsum, int n) {
  int i = blockIdx.x * 256 + threadIdx.x;
  int v = (i < n) ? deg[i] : 0;
  #pragma unroll
  for (int off = 32; off > 0; off >>= 1) v += __shfl_down(v, off, 64);
  __shared__ int ws[4];
  int lane = threadIdx.x & 63, wid = threadIdx.x >> 6;
  if (lane == 0) ws[wid] = v;
  __syncthreads();
  if (threadIdx.x == 0) bsum[blockIdx.x] = ws[0] + ws[1] + ws[2] + ws[3];
}

// Phase B: single-block exclusive scan of bsum[0..G), G <= 1024, in place.
__global__ __launch_bounds__(1024) void scanB_kernel(int* __restrict__ bsum, int G) {
  int tid = threadIdx.x;
  int v = (tid < G) ? bsum[tid] : 0;
  int lane = tid & 63, wid = tid >> 6;
  int inc = v;
  #pragma unroll
  for (int off = 1; off < 64; off <<= 1) {
    int t = __shfl_up(inc, off, 64);
    if (lane >= off) inc += t;
  }
  __shared__ int wsum[16];
  if (lane == 63) wsum[wid] = inc;
  __syncthreads();
  if (wid == 0) {
    int wv = (lane < 16) ? wsum[lane] : 0;
    #pragma unroll
    for (int off = 1; off < 16; off <<= 1) {
      int t = __shfl_up(wv, off, 64);
      if (lane >= off) wv += t;
    }
    if (lane < 16) wsum[lane] = wv;
  }
  __syncthreads();
  int excl = (wid > 0 ? wsum[wid - 1] : 0) + inc - v;
  if (tid < G) bsum[tid] = excl;
}

// Phase C: per-block local exclusive scan + block offset -> rowstart/cnt; fused dinv.
__global__ __launch_bounds__(256) void scanC_kernel(
    const int* __restrict__ deg, const int* __restrict__ boff,
    int* __restrict__ rowstart, int* __restrict__ cnt,
    float* __restrict__ dinv, int n) {
  int tid = threadIdx.x;
  int i = blockIdx.x * 256 + tid;
  int v = (i < n) ? deg[i] : 0;
  int lane = tid & 63, wid = tid >> 6;
  int inc = v;
  #pragma unroll
  for (int off = 1; off < 64; off <<= 1) {
    int t = __shfl_up(inc, off, 64);
    if (lane >= off) inc += t;
  }
  __shared__ int wsum[4];
  if (lane == 63) wsum[wid] = inc;
  __syncthreads();
  if (tid == 0) {
    int a = wsum[0], b = wsum[1], c = wsum[2];
    wsum[0] = 0; wsum[1] = a; wsum[2] = a + b; wsum[3] = a + b + c;
  }
  __syncthreads();
  int excl = boff[blockIdx.x] + wsum[wid] + inc - v;
  if (i < n) {
    rowstart[i] = excl;
    cnt[i] = excl;
    dinv[i] = rsqrtf((float)(v + 1));  // self-loop adds 1
    if (i == n - 1) rowstart[n] = excl + v;
  }
}

__global__ __launch_bounds__(256) void fill_csr_kernel(
    const int* __restrict__ ei, int* __restrict__ cnt,
    int* __restrict__ csr_src, int E) {
  int e = blockIdx.x * blockDim.x + threadIdx.x;
  if (e >= E) return;
  int src = ei[e];
  int dst = ei[E + e];
  int pos = atomicAdd(&cnt[dst], 1);
  csr_src[pos] = src;
}

// H[row, col] = (sum_k X[row,k] * W[k,col]) * dinv[row]
// block=256, TM rows/block. Each thread owns R rows x 2 cols (col, col+COUT/2).
// X tile in LDS (wave-broadcast reads), W streamed from L1/L2.
template <int CIN, int COUT, int TM>
__global__ __launch_bounds__(256) void gemm_scale_kernel(
    const float* __restrict__ X, const float* __restrict__ W,
    const float* __restrict__ dinv, float* __restrict__ H, int n) {
  constexpr int TPR = COUT / 2;   // threads per row-group (64 or 32)
  constexpr int G = 256 / TPR;    // row groups per block (4 or 8)
  constexpr int R = TM / G;       // rows per thread
  __shared__ __align__(16) float Xs[TM * CIN];

  int tid = threadIdx.x;
  int col = tid % TPR;
  int g = tid / TPR;
  int row0 = blockIdx.x * TM;

  const float4* X4 = reinterpret_cast<const float4*>(X);
  float4* Xs4 = reinterpret_cast<float4*>(Xs);
  constexpr int XV = TM * CIN / 4;
  #pragma unroll
  for (int i4 = tid; i4 < XV; i4 += 256) {
    int r = row0 + i4 / (CIN / 4);
    float4 val = make_float4(0.f, 0.f, 0.f, 0.f);
    if (r < n) val = X4[(size_t)r * (CIN / 4) + (i4 % (CIN / 4))];
    Xs4[i4] = val;
  }
  __syncthreads();

  float acc0[R], acc1[R];
  #pragma unroll
  for (int m = 0; m < R; ++m) { acc0[m] = 0.f; acc1[m] = 0.f; }

  for (int k = 0; k < CIN; k += 4) {
    float w00 = W[(k + 0) * COUT + col];
    float w01 = W[(k + 1) * COUT + col];
    float w02 = W[(k + 2) * COUT + col];
    float w03 = W[(k + 3) * COUT + col];
    float w10 = W[(k + 0) * COUT + col + TPR];
    float w11 = W[(k + 1) * COUT + col + TPR];
    float w12 = W[(k + 2) * COUT + col + TPR];
    float w13 = W[(k + 3) * COUT + col + TPR];
    #pragma unroll
    for (int m = 0; m < R; ++m) {
      const float4 xv = *reinterpret_cast<const float4*>(&Xs[(g * R + m) * CIN + k]);
      acc0[m] = fmaf(xv.x, w00, acc0[m]);
      acc0[m] = fmaf(xv.y, w01, acc0[m]);
      acc0[m] = fmaf(xv.z, w02, acc0[m]);
      acc0[m] = fmaf(xv.w, w03, acc0[m]);
      acc1[m] = fmaf(xv.x, w10, acc1[m]);
      acc1[m] = fmaf(xv.y, w11, acc1[m]);
      acc1[m] = fmaf(xv.z, w12, acc1[m]);
      acc1[m] = fmaf(xv.w, w13, acc1[m]);
    }
  }

  #pragma unroll
  for (int m = 0; m < R; ++m) {
    int row = row0 + g * R + m;
    if (row < n) {
      float di = dinv[row];
      H[(size_t)row * COUT + col] = acc0[m] * di;
      H[(size_t)row * COUT + col + TPR] = acc1[m] * di;
    }
  }
}

// out[node,:] = act( dinv[node] * (Hs[node,:] + sum_{src in row} Hs[src,:]) + bias )
// 4-deep unrolled gather: 4 independent float4 accumulators keep 4 row-loads in flight.
template <int C, bool RELU>
__global__ __launch_bounds__(256) void agg_kernel(
    const float* __restrict__ Hs, const int* __restrict__ rowstart,
    const int* __restrict__ csr_src, const float* __restrict__ dinv,
    const float* __restrict__ bias, float* __restrict__ out, int n) {
  constexpr int TPN = C / 4;        // threads per node
  constexpr int NPB = 256 / TPN;    // nodes per block
  int lane = threadIdx.x % TPN;
  int node = blockIdx.x * NPB + threadIdx.x / TPN;
  if (node >= n) return;

  const float4* H4 = reinterpret_cast<const float4*>(Hs);
  int s = rowstart[node];
  int e = rowstart[node + 1];

  float4 a0 = H4[(size_t)node * TPN + lane];  // self-loop term
  float4 a1 = make_float4(0.f, 0.f, 0.f, 0.f);
  float4 a2 = make_float4(0.f, 0.f, 0.f, 0.f);
  float4 a3 = make_float4(0.f, 0.f, 0.f, 0.f);

  int p = s;
  for (; p + 3 < e; p += 4) {
    int s0 = csr_src[p];
    int s1 = csr_src[p + 1];
    int s2 = csr_src[p + 2];
    int s3 = csr_src[p + 3];
    float4 v0 = H4[(size_t)s0 * TPN + lane];
    float4 v1 = H4[(size_t)s1 * TPN + lane];
    float4 v2 = H4[(size_t)s2 * TPN + lane];
    float4 v3 = H4[(size_t)s3 * TPN + lane];
    a0.x += v0.x; a0.y += v0.y; a0.z += v0.z; a0.w += v0.w;
    a1.x += v1.x; a1.y += v1.y; a1.z += v1.z; a1.w += v1.w;
    a2.x += v2.x; a2.y += v2.y; a2.z += v2.z; a2.w += v2.w;
    a3.x += v3.x; a3.y += v3.y; a3.z += v3.z; a3.w += v3.w;
  }
  for (; p < e; ++p) {
    int s0 = csr_src[p];
    float4 v0 = H4[(size_t)s0 * TPN + lane];
    a0.x += v0.x; a0.y += v0.y; a0.z += v0.z; a0.w += v0.w;
  }
  a0.x += a1.x + a2.x + a3.x;
  a0.y += a1.y + a2.y + a3.y;
  a0.z += a1.z + a2.z + a3.z;
  a0.w += a1.w + a2.w + a3.w;

  float di = dinv[node];
  float4 bv = reinterpret_cast<const float4*>(bias)[lane];
  float4 r;
  r.x = fmaf(a0.x, di, bv.x);
  r.y = fmaf(a0.y, di, bv.y);
  r.z = fmaf(a0.z, di, bv.z);
  r.w = fmaf(a0.w, di, bv.w);
  if (RELU) {
    r.x = fmaxf(r.x, 0.f);
    r.y = fmaxf(r.y, 0.f);
    r.z = fmaxf(r.z, 0.f);
    r.w = fmaxf(r.w, 0.f);
  }
  reinterpret_cast<float4*>(out)[(size_t)node * TPN + lane] = r;
}

extern "C" void kernel_launch(void* const* d_in, const int* in_sizes, int n_in,
                              void* d_out, int out_size, void* d_ws, size_t ws_size,
                              hipStream_t stream) {
  const float* x  = (const float*)d_in[0];
  const int*   ei = (const int*)d_in[1];
  const float* W1 = (const float*)d_in[2];
  const float* b1 = (const float*)d_in[3];
  const float* W2 = (const float*)d_in[4];
  const float* b2 = (const float*)d_in[5];
  float* out = (float*)d_out;

  const int N = in_sizes[0] / IN_C;   // 50000
  const int E = in_sizes[1] / 2;      // 800000
  const int G = (N + 255) / 256;      // scan blocks (196)

  char* ws = (char*)d_ws;
  size_t off = 0;
  auto alloc = [&](size_t bytes) -> void* {
    void* p = ws + off;
    off += (bytes + 255) & ~(size_t)255;
    return p;
  };
  int*   deg      = (int*)  alloc((size_t)N * 4);
  float* dinv     = (float*)alloc((size_t)N * 4);
  int*   rowstart = (int*)  alloc((size_t)(N + 1) * 4);
  int*   cnt      = (int*)  alloc((size_t)N * 4);
  int*   bsum     = (int*)  alloc((size_t)G * 4);
  int*   csr_src  = (int*)  alloc((size_t)E * 4);
  float* hs       = (float*)alloc((size_t)N * HID_C * 4);
  float* x2       = (float*)alloc((size_t)N * HID_C * 4);

  hipMemsetAsync(deg, 0, (size_t)N * 4, stream);
  count_deg_kernel<<<(E + 255) / 256, 256, 0, stream>>>(ei, deg, E);
  scanA_kernel<<<G, 256, 0, stream>>>(deg, bsum, N);
  scanB_kernel<<<1, 1024, 0, stream>>>(bsum, G);
  scanC_kernel<<<G, 256, 0, stream>>>(deg, bsum, rowstart, cnt, dinv, N);
  fill_csr_kernel<<<(E + 255) / 256, 256, 0, stream>>>(ei, cnt, csr_src, E);

  gemm_scale_kernel<IN_C, HID_C, 64><<<(N + 63) / 64, 256, 0, stream>>>(x, W1, dinv, hs, N);
  agg_kernel<HID_C, true><<<(N + 7) / 8, 256, 0, stream>>>(hs, rowstart, csr_src, dinv, b1, x2, N);

  gemm_scale_kernel<HID_C, OUT_C, 64><<<(N + 63) / 64, 256, 0, stream>>>(x2, W2, dinv, hs, N);
  agg_kernel<OUT_C, false><<<(N + 15) / 16, 256, 0, stream>>>(hs, rowstart, csr_src, dinv, b2, out, N);
}

// Round 4
// 215.120 us; speedup vs baseline: 1.6731x; 1.1774x over previous
//
#include <hip/hip_runtime.h>
#include <hip/hip_bf16.h>

// GCN 2-layer forward on MI355X.
// deg count -> 3-phase scan (CSR rowstart, fused dinv) -> CSR fill ->
// GEMM1(+dinv, bf16 out) -> pull-agg bf16(+b1+relu, f32 out) ->
// GEMM2(+dinv, bf16 out) -> pull-agg bf16(+b2, f32 out)

#define IN_C 128
#define HID_C 128
#define OUT_C 64

__device__ inline unsigned short f2bf_rtn(float f) {
  unsigned u = __float_as_uint(f);
  unsigned r = u + 0x7fffu + ((u >> 16) & 1u);
  return (unsigned short)(r >> 16);
}

__global__ __launch_bounds__(256) void count_deg_kernel(
    const int* __restrict__ ei, int* __restrict__ deg, int E) {
  int e = blockIdx.x * blockDim.x + threadIdx.x;
  if (e >= E) return;
  int dst = ei[E + e];
  atomicAdd(&deg[dst], 1);
}

__global__ __launch_bounds__(256) void scanA_kernel(
    const int* __restrict__ deg, int* __restrict__ bsum, int n) {
  int i = blockIdx.x * 256 + threadIdx.x;
  int v = (i < n) ? deg[i] : 0;
  #pragma unroll
  for (int off = 32; off > 0; off >>= 1) v += __shfl_down(v, off, 64);
  __shared__ int ws[4];
  int lane = threadIdx.x & 63, wid = threadIdx.x >> 6;
  if (lane == 0) ws[wid] = v;
  __syncthreads();
  if (threadIdx.x == 0) bsum[blockIdx.x] = ws[0] + ws[1] + ws[2] + ws[3];
}

__global__ __launch_bounds__(1024) void scanB_kernel(int* __restrict__ bsum, int G) {
  int tid = threadIdx.x;
  int v = (tid < G) ? bsum[tid] : 0;
  int lane = tid & 63, wid = tid >> 6;
  int inc = v;
  #pragma unroll
  for (int off = 1; off < 64; off <<= 1) {
    int t = __shfl_up(inc, off, 64);
    if (lane >= off) inc += t;
  }
  __shared__ int wsum[16];
  if (lane == 63) wsum[wid] = inc;
  __syncthreads();
  if (wid == 0) {
    int wv = (lane < 16) ? wsum[lane] : 0;
    #pragma unroll
    for (int off = 1; off < 16; off <<= 1) {
      int t = __shfl_up(wv, off, 64);
      if (lane >= off) wv += t;
    }
    if (lane < 16) wsum[lane] = wv;
  }
  __syncthreads();
  int excl = (wid > 0 ? wsum[wid - 1] : 0) + inc - v;
  if (tid < G) bsum[tid] = excl;
}

__global__ __launch_bounds__(256) void scanC_kernel(
    const int* __restrict__ deg, const int* __restrict__ boff,
    int* __restrict__ rowstart, int* __restrict__ cnt,
    float* __restrict__ dinv, int n) {
  int tid = threadIdx.x;
  int i = blockIdx.x * 256 + tid;
  int v = (i < n) ? deg[i] : 0;
  int lane = tid & 63, wid = tid >> 6;
  int inc = v;
  #pragma unroll
  for (int off = 1; off < 64; off <<= 1) {
    int t = __shfl_up(inc, off, 64);
    if (lane >= off) inc += t;
  }
  __shared__ int wsum[4];
  if (lane == 63) wsum[wid] = inc;
  __syncthreads();
  if (tid == 0) {
    int a = wsum[0], b = wsum[1], c = wsum[2];
    wsum[0] = 0; wsum[1] = a; wsum[2] = a + b; wsum[3] = a + b + c;
  }
  __syncthreads();
  int excl = boff[blockIdx.x] + wsum[wid] + inc - v;
  if (i < n) {
    rowstart[i] = excl;
    cnt[i] = excl;
    dinv[i] = rsqrtf((float)(v + 1));  // self-loop adds 1
    if (i == n - 1) rowstart[n] = excl + v;
  }
}

__global__ __launch_bounds__(256) void fill_csr_kernel(
    const int* __restrict__ ei, int* __restrict__ cnt,
    int* __restrict__ csr_src, int E) {
  int e = blockIdx.x * blockDim.x + threadIdx.x;
  if (e >= E) return;
  int src = ei[e];
  int dst = ei[E + e];
  int pos = atomicAdd(&cnt[dst], 1);
  csr_src[pos] = src;
}

// H[row, col] = (sum_k X[row,k] * W[k,col]) * dinv[row], stored as bf16.
// block=256, TM rows/block. Each thread owns R rows x 2 cols (col, col+COUT/2).
template <int CIN, int COUT, int TM>
__global__ __launch_bounds__(256) void gemm_scale_kernel(
    const float* __restrict__ X, const float* __restrict__ W,
    const float* __restrict__ dinv, unsigned short* __restrict__ H, int n) {
  constexpr int TPR = COUT / 2;
  constexpr int G = 256 / TPR;
  constexpr int R = TM / G;
  __shared__ __align__(16) float Xs[TM * CIN];

  int tid = threadIdx.x;
  int col = tid % TPR;
  int g = tid / TPR;
  int row0 = blockIdx.x * TM;

  const float4* X4 = reinterpret_cast<const float4*>(X);
  float4* Xs4 = reinterpret_cast<float4*>(Xs);
  constexpr int XV = TM * CIN / 4;
  #pragma unroll
  for (int i4 = tid; i4 < XV; i4 += 256) {
    int r = row0 + i4 / (CIN / 4);
    float4 val = make_float4(0.f, 0.f, 0.f, 0.f);
    if (r < n) val = X4[(size_t)r * (CIN / 4) + (i4 % (CIN / 4))];
    Xs4[i4] = val;
  }
  __syncthreads();

  float acc0[R], acc1[R];
  #pragma unroll
  for (int m = 0; m < R; ++m) { acc0[m] = 0.f; acc1[m] = 0.f; }

  for (int k = 0; k < CIN; k += 4) {
    float w00 = W[(k + 0) * COUT + col];
    float w01 = W[(k + 1) * COUT + col];
    float w02 = W[(k + 2) * COUT + col];
    float w03 = W[(k + 3) * COUT + col];
    float w10 = W[(k + 0) * COUT + col + TPR];
    float w11 = W[(k + 1) * COUT + col + TPR];
    float w12 = W[(k + 2) * COUT + col + TPR];
    float w13 = W[(k + 3) * COUT + col + TPR];
    #pragma unroll
    for (int m = 0; m < R; ++m) {
      const float4 xv = *reinterpret_cast<const float4*>(&Xs[(g * R + m) * CIN + k]);
      acc0[m] = fmaf(xv.x, w00, acc0[m]);
      acc0[m] = fmaf(xv.y, w01, acc0[m]);
      acc0[m] = fmaf(xv.z, w02, acc0[m]);
      acc0[m] = fmaf(xv.w, w03, acc0[m]);
      acc1[m] = fmaf(xv.x, w10, acc1[m]);
      acc1[m] = fmaf(xv.y, w11, acc1[m]);
      acc1[m] = fmaf(xv.z, w12, acc1[m]);
      acc1[m] = fmaf(xv.w, w13, acc1[m]);
    }
  }

  #pragma unroll
  for (int m = 0; m < R; ++m) {
    int row = row0 + g * R + m;
    if (row < n) {
      float di = dinv[row];
      H[(size_t)row * COUT + col] = f2bf_rtn(acc0[m] * di);
      H[(size_t)row * COUT + col + TPR] = f2bf_rtn(acc1[m] * di);
    }
  }
}

// out[node,:] = act( dinv[node] * (Hs[node,:] + sum_{src} Hs[src,:]) + bias )
// Hs is bf16 [n][C] (pre-scaled by dinv[src]); acc in f32; out f32.
// Each lane loads uint4 = 8 bf16 (16 B); TPN = C/8 lanes per node.
template <int C, bool RELU>
__global__ __launch_bounds__(256) void agg_bf16_kernel(
    const unsigned short* __restrict__ Hs, const int* __restrict__ rowstart,
    const int* __restrict__ csr_src, const float* __restrict__ dinv,
    const float* __restrict__ bias, float* __restrict__ out, int n) {
  constexpr int TPN = C / 8;        // threads per node
  constexpr int NPB = 256 / TPN;    // nodes per block
  int lane = threadIdx.x % TPN;
  int node = blockIdx.x * NPB + threadIdx.x / TPN;
  if (node >= n) return;

  const uint4* H4 = reinterpret_cast<const uint4*>(Hs);  // row stride = TPN uint4
  int s = rowstart[node];
  int e = rowstart[node + 1];

  float acc[8];
  {
    uint4 v = H4[(size_t)node * TPN + lane];  // self-loop term
    acc[0] = __uint_as_float(v.x << 16);
    acc[1] = __uint_as_float(v.x & 0xffff0000u);
    acc[2] = __uint_as_float(v.y << 16);
    acc[3] = __uint_as_float(v.y & 0xffff0000u);
    acc[4] = __uint_as_float(v.z << 16);
    acc[5] = __uint_as_float(v.z & 0xffff0000u);
    acc[6] = __uint_as_float(v.w << 16);
    acc[7] = __uint_as_float(v.w & 0xffff0000u);
  }

  int p = s;
  for (; p + 1 < e; p += 2) {
    int s0 = csr_src[p];
    int s1 = csr_src[p + 1];
    uint4 v0 = H4[(size_t)s0 * TPN + lane];
    uint4 v1 = H4[(size_t)s1 * TPN + lane];
    acc[0] += __uint_as_float(v0.x << 16);
    acc[1] += __uint_as_float(v0.x & 0xffff0000u);
    acc[2] += __uint_as_float(v0.y << 16);
    acc[3] += __uint_as_float(v0.y & 0xffff0000u);
    acc[4] += __uint_as_float(v0.z << 16);
    acc[5] += __uint_as_float(v0.z & 0xffff0000u);
    acc[6] += __uint_as_float(v0.w << 16);
    acc[7] += __uint_as_float(v0.w & 0xffff0000u);
    acc[0] += __uint_as_float(v1.x << 16);
    acc[1] += __uint_as_float(v1.x & 0xffff0000u);
    acc[2] += __uint_as_float(v1.y << 16);
    acc[3] += __uint_as_float(v1.y & 0xffff0000u);
    acc[4] += __uint_as_float(v1.z << 16);
    acc[5] += __uint_as_float(v1.z & 0xffff0000u);
    acc[6] += __uint_as_float(v1.w << 16);
    acc[7] += __uint_as_float(v1.w & 0xffff0000u);
  }
  if (p < e) {
    int s0 = csr_src[p];
    uint4 v0 = H4[(size_t)s0 * TPN + lane];
    acc[0] += __uint_as_float(v0.x << 16);
    acc[1] += __uint_as_float(v0.x & 0xffff0000u);
    acc[2] += __uint_as_float(v0.y << 16);
    acc[3] += __uint_as_float(v0.y & 0xffff0000u);
    acc[4] += __uint_as_float(v0.z << 16);
    acc[5] += __uint_as_float(v0.z & 0xffff0000u);
    acc[6] += __uint_as_float(v0.w << 16);
    acc[7] += __uint_as_float(v0.w & 0xffff0000u);
  }

  float di = dinv[node];
  float4 b0 = reinterpret_cast<const float4*>(bias)[lane * 2];
  float4 b1 = reinterpret_cast<const float4*>(bias)[lane * 2 + 1];
  float4 r0, r1;
  r0.x = fmaf(acc[0], di, b0.x);
  r0.y = fmaf(acc[1], di, b0.y);
  r0.z = fmaf(acc[2], di, b0.z);
  r0.w = fmaf(acc[3], di, b0.w);
  r1.x = fmaf(acc[4], di, b1.x);
  r1.y = fmaf(acc[5], di, b1.y);
  r1.z = fmaf(acc[6], di, b1.z);
  r1.w = fmaf(acc[7], di, b1.w);
  if (RELU) {
    r0.x = fmaxf(r0.x, 0.f); r0.y = fmaxf(r0.y, 0.f);
    r0.z = fmaxf(r0.z, 0.f); r0.w = fmaxf(r0.w, 0.f);
    r1.x = fmaxf(r1.x, 0.f); r1.y = fmaxf(r1.y, 0.f);
    r1.z = fmaxf(r1.z, 0.f); r1.w = fmaxf(r1.w, 0.f);
  }
  float4* o4 = reinterpret_cast<float4*>(out) + (size_t)node * (C / 4);
  o4[lane * 2] = r0;
  o4[lane * 2 + 1] = r1;
}

extern "C" void kernel_launch(void* const* d_in, const int* in_sizes, int n_in,
                              void* d_out, int out_size, void* d_ws, size_t ws_size,
                              hipStream_t stream) {
  const float* x  = (const float*)d_in[0];
  const int*   ei = (const int*)d_in[1];
  const float* W1 = (const float*)d_in[2];
  const float* b1 = (const float*)d_in[3];
  const float* W2 = (const float*)d_in[4];
  const float* b2 = (const float*)d_in[5];
  float* out = (float*)d_out;

  const int N = in_sizes[0] / IN_C;   // 50000
  const int E = in_sizes[1] / 2;      // 800000
  const int G = (N + 255) / 256;      // scan blocks (196)

  char* ws = (char*)d_ws;
  size_t off = 0;
  auto alloc = [&](size_t bytes) -> void* {
    void* p = ws + off;
    off += (bytes + 255) & ~(size_t)255;
    return p;
  };
  int*   deg      = (int*)  alloc((size_t)N * 4);
  float* dinv     = (float*)alloc((size_t)N * 4);
  int*   rowstart = (int*)  alloc((size_t)(N + 1) * 4);
  int*   cnt      = (int*)  alloc((size_t)N * 4);
  int*   bsum     = (int*)  alloc((size_t)G * 4);
  int*   csr_src  = (int*)  alloc((size_t)E * 4);
  unsigned short* hs = (unsigned short*)alloc((size_t)N * HID_C * 2);  // bf16, reused layer-2
  float* x2       = (float*)alloc((size_t)N * HID_C * 4);

  hipMemsetAsync(deg, 0, (size_t)N * 4, stream);
  count_deg_kernel<<<(E + 255) / 256, 256, 0, stream>>>(ei, deg, E);
  scanA_kernel<<<G, 256, 0, stream>>>(deg, bsum, N);
  scanB_kernel<<<1, 1024, 0, stream>>>(bsum, G);
  scanC_kernel<<<G, 256, 0, stream>>>(deg, bsum, rowstart, cnt, dinv, N);
  fill_csr_kernel<<<(E + 255) / 256, 256, 0, stream>>>(ei, cnt, csr_src, E);

  gemm_scale_kernel<IN_C, HID_C, 64><<<(N + 63) / 64, 256, 0, stream>>>(x, W1, dinv, hs, N);
  agg_bf16_kernel<HID_C, true><<<(N + 15) / 16, 256, 0, stream>>>(hs, rowstart, csr_src, dinv, b1, x2, N);

  gemm_scale_kernel<HID_C, OUT_C, 64><<<(N + 63) / 64, 256, 0, stream>>>(x2, W2, dinv, hs, N);
  agg_bf16_kernel<OUT_C, false><<<(N + 31) / 32, 256, 0, stream>>>(hs, rowstart, csr_src, dinv, b2, out, N);
}

// Round 5
// 181.542 us; speedup vs baseline: 1.9826x; 1.1850x over previous
//
#include <hip/hip_runtime.h>
#include <hip/hip_bf16.h>

// GCN 2-layer forward on MI355X.
// phase1 (bucket scatter of packed edges) -> bucket_scan (196 totals) ->
// phase2 (per-bucket LDS hist/scan -> rowstart+dinv+csr) ->
// GEMM1(+dinv, bf16 out) -> pull-agg bf16(+b1+relu) -> GEMM2 -> pull-agg(+b2)

#define IN_C 128
#define HID_C 128
#define OUT_C 64
#define BKT_SH 8                 // 256 nodes per bucket
#define BKT_NODES 256
#define NSLICE 8                 // per-bucket slices (XCD proxy via blockIdx&7)
#define CAP 768                  // capacity per (bucket,slice) region; mean=510
#define OVF_CAP 65536

__device__ inline unsigned short f2bf_rtn(float f) {
  unsigned u = __float_as_uint(f);
  unsigned r = u + 0x7fffu + ((u >> 16) & 1u);
  return (unsigned short)(r >> 16);
}

// Phase 1: per edge, append packed (src | dst_local<<16) to region (bucket, slice).
// bcnt cursors padded to 64B (stride 16 ints) to avoid cross-counter line bouncing.
__global__ __launch_bounds__(256) void phase1_bucket_kernel(
    const int* __restrict__ ei, unsigned* __restrict__ pairs,
    int* __restrict__ bcnt, uint2* __restrict__ ovf, int* __restrict__ ovf_cnt,
    int* __restrict__ ovfb, int E) {
  int e = blockIdx.x * 256 + threadIdx.x;
  if (e >= E) return;
  int src = ei[e];
  int dst = ei[E + e];
  int b = dst >> BKT_SH;
  int s = blockIdx.x & (NSLICE - 1);
  int cell = b * NSLICE + s;
  int pos = atomicAdd(&bcnt[cell * 16], 1);
  unsigned w = (unsigned)src | ((unsigned)(dst & (BKT_NODES - 1)) << 16);
  if (pos < CAP) {
    pairs[(size_t)cell * CAP + pos] = w;
  } else {
    int oi = atomicAdd(ovf_cnt, 1);
    if (oi < OVF_CAP) {
      ovf[oi] = make_uint2((unsigned)src, (unsigned)dst);
      atomicAdd(&ovfb[b], 1);
    }
  }
}

// Single block: bucket totals -> exclusive scan -> bucket_base[0..K]; rowstart[N]=total.
__global__ __launch_bounds__(256) void bucket_scan_kernel(
    const int* __restrict__ bcnt, const int* __restrict__ ovfb,
    int* __restrict__ bucket_base, int* __restrict__ rowstart, int K, int N) {
  int t = threadIdx.x;
  int tot = 0;
  if (t < K) {
    #pragma unroll
    for (int s = 0; s < NSLICE; ++s) {
      int c = bcnt[(t * NSLICE + s) * 16];
      tot += (c < CAP) ? c : CAP;
    }
    tot += ovfb[t];
  }
  int lane = t & 63, wid = t >> 6;
  int inc = tot;
  #pragma unroll
  for (int off = 1; off < 64; off <<= 1) {
    int u = __shfl_up(inc, off, 64);
    if (lane >= off) inc += u;
  }
  __shared__ int ws4[4];
  if (lane == 63) ws4[wid] = inc;
  __syncthreads();
  if (t == 0) {
    int a = ws4[0], b = ws4[1], c = ws4[2];
    ws4[0] = 0; ws4[1] = a; ws4[2] = a + b; ws4[3] = a + b + c;
  }
  __syncthreads();
  int excl = ws4[wid] + inc - tot;
  if (t <= K) bucket_base[t] = excl;
  if (t == K) rowstart[N] = excl;  // = total edge count placed
}

// Phase 2: one block per bucket. LDS hist over dst_local -> scan -> rowstart/dinv,
// then scatter src into csr (uint16) within the block-owned region.
__global__ __launch_bounds__(256) void phase2_csr_kernel(
    const unsigned* __restrict__ pairs, const int* __restrict__ bcnt,
    const uint2* __restrict__ ovf, const int* __restrict__ ovf_cnt,
    const int* __restrict__ bucket_base, int* __restrict__ rowstart,
    float* __restrict__ dinv, unsigned short* __restrict__ csr, int N) {
  int b = blockIdx.x;
  int t = threadIdx.x;
  __shared__ int hist[BKT_NODES];
  __shared__ int cur[BKT_NODES];
  hist[t] = 0;
  __syncthreads();

  int cnts[NSLICE];
  #pragma unroll
  for (int s = 0; s < NSLICE; ++s) {
    int c = bcnt[(b * NSLICE + s) * 16];
    cnts[s] = (c < CAP) ? c : CAP;
  }

  #pragma unroll
  for (int s = 0; s < NSLICE; ++s) {
    const unsigned* reg = pairs + (size_t)(b * NSLICE + s) * CAP;
    for (int i = t; i < cnts[s]; i += 256)
      atomicAdd(&hist[reg[i] >> 16], 1);
  }
  int oc = *ovf_cnt;
  if (oc > OVF_CAP) oc = OVF_CAP;
  for (int i = t; i < oc; i += 256) {
    uint2 p = ovf[i];
    if ((int)(p.y >> BKT_SH) == b) atomicAdd(&hist[p.y & (BKT_NODES - 1)], 1);
  }
  __syncthreads();

  // exclusive scan of hist[256]
  int v = hist[t];
  int lane = t & 63, wid = t >> 6;
  int inc = v;
  #pragma unroll
  for (int off = 1; off < 64; off <<= 1) {
    int u = __shfl_up(inc, off, 64);
    if (lane >= off) inc += u;
  }
  __shared__ int ws4[4];
  if (lane == 63) ws4[wid] = inc;
  __syncthreads();
  if (t == 0) {
    int a = ws4[0], bb = ws4[1], c = ws4[2];
    ws4[0] = 0; ws4[1] = a; ws4[2] = a + bb; ws4[3] = a + bb + c;
  }
  __syncthreads();
  int excl = ws4[wid] + inc - v;

  int base = bucket_base[b];
  int node = b * BKT_NODES + t;
  if (node < N) {
    rowstart[node] = base + excl;
    dinv[node] = rsqrtf((float)(v + 1));  // +1 self-loop
  }
  cur[t] = base + excl;
  __syncthreads();

  #pragma unroll
  for (int s = 0; s < NSLICE; ++s) {
    const unsigned* reg = pairs + (size_t)(b * NSLICE + s) * CAP;
    for (int i = t; i < cnts[s]; i += 256) {
      unsigned w = reg[i];
      int pos = atomicAdd(&cur[w >> 16], 1);
      csr[pos] = (unsigned short)(w & 0xffffu);
    }
  }
  for (int i = t; i < oc; i += 256) {
    uint2 p = ovf[i];
    if ((int)(p.y >> BKT_SH) == b) {
      int pos = atomicAdd(&cur[p.y & (BKT_NODES - 1)], 1);
      csr[pos] = (unsigned short)p.x;
    }
  }
}

// H[row, col] = (sum_k X[row,k] * W[k,col]) * dinv[row], stored as bf16.
template <int CIN, int COUT, int TM>
__global__ __launch_bounds__(256) void gemm_scale_kernel(
    const float* __restrict__ X, const float* __restrict__ W,
    const float* __restrict__ dinv, unsigned short* __restrict__ H, int n) {
  constexpr int TPR = COUT / 2;
  constexpr int G = 256 / TPR;
  constexpr int R = TM / G;
  __shared__ __align__(16) float Xs[TM * CIN];

  int tid = threadIdx.x;
  int col = tid % TPR;
  int g = tid / TPR;
  int row0 = blockIdx.x * TM;

  const float4* X4 = reinterpret_cast<const float4*>(X);
  float4* Xs4 = reinterpret_cast<float4*>(Xs);
  constexpr int XV = TM * CIN / 4;
  #pragma unroll
  for (int i4 = tid; i4 < XV; i4 += 256) {
    int r = row0 + i4 / (CIN / 4);
    float4 val = make_float4(0.f, 0.f, 0.f, 0.f);
    if (r < n) val = X4[(size_t)r * (CIN / 4) + (i4 % (CIN / 4))];
    Xs4[i4] = val;
  }
  __syncthreads();

  float acc0[R], acc1[R];
  #pragma unroll
  for (int m = 0; m < R; ++m) { acc0[m] = 0.f; acc1[m] = 0.f; }

  for (int k = 0; k < CIN; k += 4) {
    float w00 = W[(k + 0) * COUT + col];
    float w01 = W[(k + 1) * COUT + col];
    float w02 = W[(k + 2) * COUT + col];
    float w03 = W[(k + 3) * COUT + col];
    float w10 = W[(k + 0) * COUT + col + TPR];
    float w11 = W[(k + 1) * COUT + col + TPR];
    float w12 = W[(k + 2) * COUT + col + TPR];
    float w13 = W[(k + 3) * COUT + col + TPR];
    #pragma unroll
    for (int m = 0; m < R; ++m) {
      const float4 xv = *reinterpret_cast<const float4*>(&Xs[(g * R + m) * CIN + k]);
      acc0[m] = fmaf(xv.x, w00, acc0[m]);
      acc0[m] = fmaf(xv.y, w01, acc0[m]);
      acc0[m] = fmaf(xv.z, w02, acc0[m]);
      acc0[m] = fmaf(xv.w, w03, acc0[m]);
      acc1[m] = fmaf(xv.x, w10, acc1[m]);
      acc1[m] = fmaf(xv.y, w11, acc1[m]);
      acc1[m] = fmaf(xv.z, w12, acc1[m]);
      acc1[m] = fmaf(xv.w, w13, acc1[m]);
    }
  }

  #pragma unroll
  for (int m = 0; m < R; ++m) {
    int row = row0 + g * R + m;
    if (row < n) {
      float di = dinv[row];
      H[(size_t)row * COUT + col] = f2bf_rtn(acc0[m] * di);
      H[(size_t)row * COUT + col + TPR] = f2bf_rtn(acc1[m] * di);
    }
  }
}

// out[node,:] = act( dinv[node] * (Hs[node,:] + sum_{src} Hs[src,:]) + bias )
template <int C, bool RELU>
__global__ __launch_bounds__(256) void agg_bf16_kernel(
    const unsigned short* __restrict__ Hs, const int* __restrict__ rowstart,
    const unsigned short* __restrict__ csr, const float* __restrict__ dinv,
    const float* __restrict__ bias, float* __restrict__ out, int n) {
  constexpr int TPN = C / 8;
  constexpr int NPB = 256 / TPN;
  int lane = threadIdx.x % TPN;
  int node = blockIdx.x * NPB + threadIdx.x / TPN;
  if (node >= n) return;

  const uint4* H4 = reinterpret_cast<const uint4*>(Hs);
  int s = rowstart[node];
  int e = rowstart[node + 1];

  float acc[8];
  {
    uint4 v = H4[(size_t)node * TPN + lane];
    acc[0] = __uint_as_float(v.x << 16);
    acc[1] = __uint_as_float(v.x & 0xffff0000u);
    acc[2] = __uint_as_float(v.y << 16);
    acc[3] = __uint_as_float(v.y & 0xffff0000u);
    acc[4] = __uint_as_float(v.z << 16);
    acc[5] = __uint_as_float(v.z & 0xffff0000u);
    acc[6] = __uint_as_float(v.w << 16);
    acc[7] = __uint_as_float(v.w & 0xffff0000u);
  }

  int p = s;
  for (; p + 1 < e; p += 2) {
    int s0 = csr[p];
    int s1 = csr[p + 1];
    uint4 v0 = H4[(size_t)s0 * TPN + lane];
    uint4 v1 = H4[(size_t)s1 * TPN + lane];
    acc[0] += __uint_as_float(v0.x << 16);
    acc[1] += __uint_as_float(v0.x & 0xffff0000u);
    acc[2] += __uint_as_float(v0.y << 16);
    acc[3] += __uint_as_float(v0.y & 0xffff0000u);
    acc[4] += __uint_as_float(v0.z << 16);
    acc[5] += __uint_as_float(v0.z & 0xffff0000u);
    acc[6] += __uint_as_float(v0.w << 16);
    acc[7] += __uint_as_float(v0.w & 0xffff0000u);
    acc[0] += __uint_as_float(v1.x << 16);
    acc[1] += __uint_as_float(v1.x & 0xffff0000u);
    acc[2] += __uint_as_float(v1.y << 16);
    acc[3] += __uint_as_float(v1.y & 0xffff0000u);
    acc[4] += __uint_as_float(v1.z << 16);
    acc[5] += __uint_as_float(v1.z & 0xffff0000u);
    acc[6] += __uint_as_float(v1.w << 16);
    acc[7] += __uint_as_float(v1.w & 0xffff0000u);
  }
  if (p < e) {
    int s0 = csr[p];
    uint4 v0 = H4[(size_t)s0 * TPN + lane];
    acc[0] += __uint_as_float(v0.x << 16);
    acc[1] += __uint_as_float(v0.x & 0xffff0000u);
    acc[2] += __uint_as_float(v0.y << 16);
    acc[3] += __uint_as_float(v0.y & 0xffff0000u);
    acc[4] += __uint_as_float(v0.z << 16);
    acc[5] += __uint_as_float(v0.z & 0xffff0000u);
    acc[6] += __uint_as_float(v0.w << 16);
    acc[7] += __uint_as_float(v0.w & 0xffff0000u);
  }

  float di = dinv[node];
  float4 b0 = reinterpret_cast<const float4*>(bias)[lane * 2];
  float4 b1 = reinterpret_cast<const float4*>(bias)[lane * 2 + 1];
  float4 r0, r1;
  r0.x = fmaf(acc[0], di, b0.x);
  r0.y = fmaf(acc[1], di, b0.y);
  r0.z = fmaf(acc[2], di, b0.z);
  r0.w = fmaf(acc[3], di, b0.w);
  r1.x = fmaf(acc[4], di, b1.x);
  r1.y = fmaf(acc[5], di, b1.y);
  r1.z = fmaf(acc[6], di, b1.z);
  r1.w = fmaf(acc[7], di, b1.w);
  if (RELU) {
    r0.x = fmaxf(r0.x, 0.f); r0.y = fmaxf(r0.y, 0.f);
    r0.z = fmaxf(r0.z, 0.f); r0.w = fmaxf(r0.w, 0.f);
    r1.x = fmaxf(r1.x, 0.f); r1.y = fmaxf(r1.y, 0.f);
    r1.z = fmaxf(r1.z, 0.f); r1.w = fmaxf(r1.w, 0.f);
  }
  float4* o4 = reinterpret_cast<float4*>(out) + (size_t)node * (C / 4);
  o4[lane * 2] = r0;
  o4[lane * 2 + 1] = r1;
}

extern "C" void kernel_launch(void* const* d_in, const int* in_sizes, int n_in,
                              void* d_out, int out_size, void* d_ws, size_t ws_size,
                              hipStream_t stream) {
  const float* x  = (const float*)d_in[0];
  const int*   ei = (const int*)d_in[1];
  const float* W1 = (const float*)d_in[2];
  const float* b1 = (const float*)d_in[3];
  const float* W2 = (const float*)d_in[4];
  const float* b2 = (const float*)d_in[5];
  float* out = (float*)d_out;

  const int N = in_sizes[0] / IN_C;        // 50000
  const int E = in_sizes[1] / 2;           // 800000
  const int K = (N + BKT_NODES - 1) >> BKT_SH;  // 196 buckets

  char* ws = (char*)d_ws;
  size_t off = 0;
  auto alloc = [&](size_t bytes) -> void* {
    void* p = ws + off;
    off += (bytes + 255) & ~(size_t)255;
    return p;
  };
  // zeroed region (contiguous): bcnt (padded) + ovf_cnt + ovfb
  int* bcnt    = (int*)alloc((size_t)K * NSLICE * 16 * 4);  // 64B-padded cursors
  int* ovf_cnt = (int*)alloc(4);
  int* ovfb    = (int*)alloc((size_t)K * 4);
  size_t zero_bytes = off;  // everything so far starts at ws+0

  int*   bucket_base = (int*)  alloc((size_t)(K + 1) * 4);
  int*   rowstart    = (int*)  alloc((size_t)(N + 1) * 4);
  float* dinv        = (float*)alloc((size_t)N * 4);
  unsigned* pairs    = (unsigned*)alloc((size_t)K * NSLICE * CAP * 4);
  uint2* ovf         = (uint2*)alloc((size_t)OVF_CAP * 8);
  unsigned short* csr = (unsigned short*)alloc((size_t)E * 2);
  unsigned short* hs = (unsigned short*)alloc((size_t)N * HID_C * 2);
  float* x2          = (float*)alloc((size_t)N * HID_C * 4);

  hipMemsetAsync(ws, 0, zero_bytes, stream);
  phase1_bucket_kernel<<<(E + 255) / 256, 256, 0, stream>>>(
      ei, pairs, bcnt, ovf, ovf_cnt, ovfb, E);
  bucket_scan_kernel<<<1, 256, 0, stream>>>(bcnt, ovfb, bucket_base, rowstart, K, N);
  phase2_csr_kernel<<<K, 256, 0, stream>>>(
      pairs, bcnt, ovf, ovf_cnt, bucket_base, rowstart, dinv, csr, N);

  gemm_scale_kernel<IN_C, HID_C, 64><<<(N + 63) / 64, 256, 0, stream>>>(x, W1, dinv, hs, N);
  agg_bf16_kernel<HID_C, true><<<(N + 15) / 16, 256, 0, stream>>>(hs, rowstart, csr, dinv, b1, x2, N);

  gemm_scale_kernel<HID_C, OUT_C, 64><<<(N + 63) / 64, 256, 0, stream>>>(x2, W2, dinv, hs, N);
  agg_bf16_kernel<OUT_C, false><<<(N + 31) / 32, 256, 0, stream>>>(hs, rowstart, csr, dinv, b2, out, N);
}

// Round 6
// 155.789 us; speedup vs baseline: 2.3103x; 1.1653x over previous
//
#include <hip/hip_runtime.h>
#include <hip/hip_bf16.h>

// GCN 2-layer forward on MI355X.
// wt (W->Wt bf16) -> phase1 (bucket scatter) -> bucket_scan -> phase2 (CSR+dinv) ->
// MFMA-GEMM1 (f32 X -> bf16 hs, *dinv) -> agg1 (bf16 in, bf16 out, +b1+relu) ->
// MFMA-GEMM2 (bf16 x2 -> bf16 hs, *dinv) -> agg2 (bf16 in, f32 out, +b2)

#define IN_C 128
#define HID_C 128
#define OUT_C 64
#define BKT_SH 8
#define BKT_NODES 256
#define NSLICE 8
#define CAP 768
#define OVF_CAP 65536

typedef float f32x4 __attribute__((ext_vector_type(4)));
typedef short bf16x8 __attribute__((ext_vector_type(8)));

__device__ inline unsigned short f2bf_rtn(float f) {
  unsigned u = __float_as_uint(f);
  unsigned r = u + 0x7fffu + ((u >> 16) & 1u);
  return (unsigned short)(r >> 16);
}
__device__ inline unsigned pack_bf2(float a, float b) {
  return (unsigned)f2bf_rtn(a) | ((unsigned)f2bf_rtn(b) << 16);
}

// ---- W transpose + bf16 convert: w1t[n][k], w2t[n][k] ----
__global__ __launch_bounds__(256) void wt_kernel(
    const float* __restrict__ W1, const float* __restrict__ W2,
    short* __restrict__ w1t, short* __restrict__ w2t) {
  int i = blockIdx.x * 256 + threadIdx.x;
  if (i < IN_C * HID_C) {
    int n = i >> 7, k = i & 127;
    w1t[i] = (short)f2bf_rtn(W1[k * HID_C + n]);
  }
  if (i < HID_C * OUT_C) {
    int n = i >> 7, k = i & 127;
    w2t[i] = (short)f2bf_rtn(W2[k * OUT_C + n]);
  }
}

// ---- CSR build (bucket sort) ----
__global__ __launch_bounds__(256) void phase1_bucket_kernel(
    const int* __restrict__ ei, unsigned* __restrict__ pairs,
    int* __restrict__ bcnt, uint2* __restrict__ ovf, int* __restrict__ ovf_cnt,
    int* __restrict__ ovfb, int E) {
  int e = blockIdx.x * 256 + threadIdx.x;
  if (e >= E) return;
  int src = ei[e];
  int dst = ei[E + e];
  int b = dst >> BKT_SH;
  int s = blockIdx.x & (NSLICE - 1);
  int cell = b * NSLICE + s;
  int pos = atomicAdd(&bcnt[cell * 16], 1);
  unsigned w = (unsigned)src | ((unsigned)(dst & (BKT_NODES - 1)) << 16);
  if (pos < CAP) {
    pairs[(size_t)cell * CAP + pos] = w;
  } else {
    int oi = atomicAdd(ovf_cnt, 1);
    if (oi < OVF_CAP) {
      ovf[oi] = make_uint2((unsigned)src, (unsigned)dst);
      atomicAdd(&ovfb[b], 1);
    }
  }
}

__global__ __launch_bounds__(256) void bucket_scan_kernel(
    const int* __restrict__ bcnt, const int* __restrict__ ovfb,
    int* __restrict__ bucket_base, int* __restrict__ rowstart, int K, int N) {
  int t = threadIdx.x;
  int tot = 0;
  if (t < K) {
    #pragma unroll
    for (int s = 0; s < NSLICE; ++s) {
      int c = bcnt[(t * NSLICE + s) * 16];
      tot += (c < CAP) ? c : CAP;
    }
    tot += ovfb[t];
  }
  int lane = t & 63, wid = t >> 6;
  int inc = tot;
  #pragma unroll
  for (int off = 1; off < 64; off <<= 1) {
    int u = __shfl_up(inc, off, 64);
    if (lane >= off) inc += u;
  }
  __shared__ int ws4[4];
  if (lane == 63) ws4[wid] = inc;
  __syncthreads();
  if (t == 0) {
    int a = ws4[0], b = ws4[1], c = ws4[2];
    ws4[0] = 0; ws4[1] = a; ws4[2] = a + b; ws4[3] = a + b + c;
  }
  __syncthreads();
  int excl = ws4[wid] + inc - tot;
  if (t <= K) bucket_base[t] = excl;
  if (t == K) rowstart[N] = excl;
}

__global__ __launch_bounds__(256) void phase2_csr_kernel(
    const unsigned* __restrict__ pairs, const int* __restrict__ bcnt,
    const uint2* __restrict__ ovf, const int* __restrict__ ovf_cnt,
    const int* __restrict__ bucket_base, int* __restrict__ rowstart,
    float* __restrict__ dinv, unsigned short* __restrict__ csr, int N) {
  int b = blockIdx.x;
  int t = threadIdx.x;
  __shared__ int hist[BKT_NODES];
  __shared__ int cur[BKT_NODES];
  hist[t] = 0;
  __syncthreads();

  int cnts[NSLICE];
  #pragma unroll
  for (int s = 0; s < NSLICE; ++s) {
    int c = bcnt[(b * NSLICE + s) * 16];
    cnts[s] = (c < CAP) ? c : CAP;
  }

  #pragma unroll
  for (int s = 0; s < NSLICE; ++s) {
    const unsigned* reg = pairs + (size_t)(b * NSLICE + s) * CAP;
    for (int i = t; i < cnts[s]; i += 256)
      atomicAdd(&hist[reg[i] >> 16], 1);
  }
  int oc = *ovf_cnt;
  if (oc > OVF_CAP) oc = OVF_CAP;
  for (int i = t; i < oc; i += 256) {
    uint2 p = ovf[i];
    if ((int)(p.y >> BKT_SH) == b) atomicAdd(&hist[p.y & (BKT_NODES - 1)], 1);
  }
  __syncthreads();

  int v = hist[t];
  int lane = t & 63, wid = t >> 6;
  int inc = v;
  #pragma unroll
  for (int off = 1; off < 64; off <<= 1) {
    int u = __shfl_up(inc, off, 64);
    if (lane >= off) inc += u;
  }
  __shared__ int ws4[4];
  if (lane == 63) ws4[wid] = inc;
  __syncthreads();
  if (t == 0) {
    int a = ws4[0], bb = ws4[1], c = ws4[2];
    ws4[0] = 0; ws4[1] = a; ws4[2] = a + bb; ws4[3] = a + bb + c;
  }
  __syncthreads();
  int excl = ws4[wid] + inc - v;

  int base = bucket_base[b];
  int node = b * BKT_NODES + t;
  if (node < N) {
    rowstart[node] = base + excl;
    dinv[node] = rsqrtf((float)(v + 1));
  }
  cur[t] = base + excl;
  __syncthreads();

  #pragma unroll
  for (int s = 0; s < NSLICE; ++s) {
    const unsigned* reg = pairs + (size_t)(b * NSLICE + s) * CAP;
    for (int i = t; i < cnts[s]; i += 256) {
      unsigned w = reg[i];
      int pos = atomicAdd(&cur[w >> 16], 1);
      csr[pos] = (unsigned short)(w & 0xffffu);
    }
  }
  for (int i = t; i < oc; i += 256) {
    uint2 p = ovf[i];
    if ((int)(p.y >> BKT_SH) == b) {
      int pos = atomicAdd(&cur[p.y & (BKT_NODES - 1)], 1);
      csr[pos] = (unsigned short)p.x;
    }
  }
}

// ---- MFMA GEMM: H[r][c] = bf16( (X[r,:] @ W[:,c]) * dinv[r] ) ----
// One 16-row tile per wave; 4 waves/block; no LDS, no barriers.
// A-frag: lane holds X[tile*16 + (l&15)][kt*32 + (l>>4)*8 + 0..7]  (16B)
// B-frag: lane holds Wt[ct*16 + (l&15)][kt*32 + (l>>4)*8 + 0..7]   (16B, L1-hot)
// C:      col = l&15, row = tile*16 + (l>>4)*4 + reg               (m89/m91)
template <int COUT, bool ABF16>
__global__ __launch_bounds__(256) void mfma_gemm_kernel(
    const void* __restrict__ Xv, const short* __restrict__ Wt,
    const float* __restrict__ dinv, unsigned short* __restrict__ H, int ntiles) {
  int lane = threadIdx.x & 63;
  int tile = blockIdx.x * 4 + (threadIdx.x >> 6);
  if (tile >= ntiles) return;
  constexpr int NT = COUT / 16;

  int arow = tile * 16 + (lane & 15);
  int kch = (lane >> 4) * 8;  // 0,8,16,24

  bf16x8 afrag[4];
  if (ABF16) {
    const bf16x8* Xb = (const bf16x8*)Xv;  // row = 16 chunks of 8 bf16
    #pragma unroll
    for (int kt = 0; kt < 4; ++kt)
      afrag[kt] = Xb[(size_t)arow * 16 + (kt * 32 + kch) / 8];
  } else {
    const float4* Xf = (const float4*)Xv;  // row = 32 float4
    #pragma unroll
    for (int kt = 0; kt < 4; ++kt) {
      float4 f0 = Xf[(size_t)arow * 32 + (kt * 32 + kch) / 4];
      float4 f1 = Xf[(size_t)arow * 32 + (kt * 32 + kch) / 4 + 1];
      bf16x8 a;
      a[0] = (short)f2bf_rtn(f0.x); a[1] = (short)f2bf_rtn(f0.y);
      a[2] = (short)f2bf_rtn(f0.z); a[3] = (short)f2bf_rtn(f0.w);
      a[4] = (short)f2bf_rtn(f1.x); a[5] = (short)f2bf_rtn(f1.y);
      a[6] = (short)f2bf_rtn(f1.z); a[7] = (short)f2bf_rtn(f1.w);
      afrag[kt] = a;
    }
  }

  const bf16x8* W8 = (const bf16x8*)Wt;
  f32x4 zero = {0.f, 0.f, 0.f, 0.f};
  f32x4 acc[NT];
  #pragma unroll
  for (int ct = 0; ct < NT; ++ct) acc[ct] = zero;

  #pragma unroll
  for (int ct = 0; ct < NT; ++ct) {
    int bcol = ct * 16 + (lane & 15);
    #pragma unroll
    for (int kt = 0; kt < 4; ++kt) {
      bf16x8 b = W8[bcol * 16 + (kt * 32 + kch) / 8];
      acc[ct] = __builtin_amdgcn_mfma_f32_16x16x32_bf16(afrag[kt], b, acc[ct], 0, 0, 0);
    }
  }

  int r0 = tile * 16 + (lane >> 4) * 4;
  float di[4];
  #pragma unroll
  for (int j = 0; j < 4; ++j) di[j] = dinv[r0 + j];
  #pragma unroll
  for (int ct = 0; ct < NT; ++ct) {
    #pragma unroll
    for (int j = 0; j < 4; ++j)
      H[(size_t)(r0 + j) * COUT + ct * 16 + (lane & 15)] = f2bf_rtn(acc[ct][j] * di[j]);
  }
}

// ---- pull-agg: out[node,:] = act( dinv[node]*(Hs[node,:]+sum Hs[src,:]) + bias ) ----
template <int C, bool RELU, bool OUT_BF16>
__global__ __launch_bounds__(256) void agg_bf16_kernel(
    const unsigned short* __restrict__ Hs, const int* __restrict__ rowstart,
    const unsigned short* __restrict__ csr, const float* __restrict__ dinv,
    const float* __restrict__ bias, void* __restrict__ out, int n) {
  constexpr int TPN = C / 8;
  constexpr int NPB = 256 / TPN;
  int lane = threadIdx.x % TPN;
  int node = blockIdx.x * NPB + threadIdx.x / TPN;
  if (node >= n) return;

  const uint4* H4 = reinterpret_cast<const uint4*>(Hs);
  int s = rowstart[node];
  int e = rowstart[node + 1];

  float acc[8];
  {
    uint4 v = H4[(size_t)node * TPN + lane];
    acc[0] = __uint_as_float(v.x << 16);
    acc[1] = __uint_as_float(v.x & 0xffff0000u);
    acc[2] = __uint_as_float(v.y << 16);
    acc[3] = __uint_as_float(v.y & 0xffff0000u);
    acc[4] = __uint_as_float(v.z << 16);
    acc[5] = __uint_as_float(v.z & 0xffff0000u);
    acc[6] = __uint_as_float(v.w << 16);
    acc[7] = __uint_as_float(v.w & 0xffff0000u);
  }

  int p = s;
  for (; p + 1 < e; p += 2) {
    int s0 = csr[p];
    int s1 = csr[p + 1];
    uint4 v0 = H4[(size_t)s0 * TPN + lane];
    uint4 v1 = H4[(size_t)s1 * TPN + lane];
    acc[0] += __uint_as_float(v0.x << 16);
    acc[1] += __uint_as_float(v0.x & 0xffff0000u);
    acc[2] += __uint_as_float(v0.y << 16);
    acc[3] += __uint_as_float(v0.y & 0xffff0000u);
    acc[4] += __uint_as_float(v0.z << 16);
    acc[5] += __uint_as_float(v0.z & 0xffff0000u);
    acc[6] += __uint_as_float(v0.w << 16);
    acc[7] += __uint_as_float(v0.w & 0xffff0000u);
    acc[0] += __uint_as_float(v1.x << 16);
    acc[1] += __uint_as_float(v1.x & 0xffff0000u);
    acc[2] += __uint_as_float(v1.y << 16);
    acc[3] += __uint_as_float(v1.y & 0xffff0000u);
    acc[4] += __uint_as_float(v1.z << 16);
    acc[5] += __uint_as_float(v1.z & 0xffff0000u);
    acc[6] += __uint_as_float(v1.w << 16);
    acc[7] += __uint_as_float(v1.w & 0xffff0000u);
  }
  if (p < e) {
    int s0 = csr[p];
    uint4 v0 = H4[(size_t)s0 * TPN + lane];
    acc[0] += __uint_as_float(v0.x << 16);
    acc[1] += __uint_as_float(v0.x & 0xffff0000u);
    acc[2] += __uint_as_float(v0.y << 16);
    acc[3] += __uint_as_float(v0.y & 0xffff0000u);
    acc[4] += __uint_as_float(v0.z << 16);
    acc[5] += __uint_as_float(v0.z & 0xffff0000u);
    acc[6] += __uint_as_float(v0.w << 16);
    acc[7] += __uint_as_float(v0.w & 0xffff0000u);
  }

  float di = dinv[node];
  float4 b0 = reinterpret_cast<const float4*>(bias)[lane * 2];
  float4 b1 = reinterpret_cast<const float4*>(bias)[lane * 2 + 1];
  float r[8];
  r[0] = fmaf(acc[0], di, b0.x);
  r[1] = fmaf(acc[1], di, b0.y);
  r[2] = fmaf(acc[2], di, b0.z);
  r[3] = fmaf(acc[3], di, b0.w);
  r[4] = fmaf(acc[4], di, b1.x);
  r[5] = fmaf(acc[5], di, b1.y);
  r[6] = fmaf(acc[6], di, b1.z);
  r[7] = fmaf(acc[7], di, b1.w);
  if (RELU) {
    #pragma unroll
    for (int j = 0; j < 8; ++j) r[j] = fmaxf(r[j], 0.f);
  }
  if (OUT_BF16) {
    uint4 o;
    o.x = pack_bf2(r[0], r[1]);
    o.y = pack_bf2(r[2], r[3]);
    o.z = pack_bf2(r[4], r[5]);
    o.w = pack_bf2(r[6], r[7]);
    reinterpret_cast<uint4*>(out)[(size_t)node * TPN + lane] = o;
  } else {
    float4* o4 = reinterpret_cast<float4*>(out) + (size_t)node * (C / 4);
    o4[lane * 2] = make_float4(r[0], r[1], r[2], r[3]);
    o4[lane * 2 + 1] = make_float4(r[4], r[5], r[6], r[7]);
  }
}

extern "C" void kernel_launch(void* const* d_in, const int* in_sizes, int n_in,
                              void* d_out, int out_size, void* d_ws, size_t ws_size,
                              hipStream_t stream) {
  const float* x  = (const float*)d_in[0];
  const int*   ei = (const int*)d_in[1];
  const float* W1 = (const float*)d_in[2];
  const float* b1 = (const float*)d_in[3];
  const float* W2 = (const float*)d_in[4];
  const float* b2 = (const float*)d_in[5];
  float* out = (float*)d_out;

  const int N = in_sizes[0] / IN_C;             // 50000
  const int E = in_sizes[1] / 2;                // 800000
  const int K = (N + BKT_NODES - 1) >> BKT_SH;  // 196 buckets
  const int NTILES = (N + 15) / 16;             // 3125 (exact)

  char* ws = (char*)d_ws;
  size_t off = 0;
  auto alloc = [&](size_t bytes) -> void* {
    void* p = ws + off;
    off += (bytes + 255) & ~(size_t)255;
    return p;
  };
  int* bcnt    = (int*)alloc((size_t)K * NSLICE * 16 * 4);
  int* ovf_cnt = (int*)alloc(4);
  int* ovfb    = (int*)alloc((size_t)K * 4);
  size_t zero_bytes = off;

  int*   bucket_base = (int*)  alloc((size_t)(K + 1) * 4);
  int*   rowstart    = (int*)  alloc((size_t)(N + 1) * 4);
  float* dinv        = (float*)alloc((size_t)N * 4);
  unsigned* pairs    = (unsigned*)alloc((size_t)K * NSLICE * CAP * 4);
  uint2* ovf         = (uint2*)alloc((size_t)OVF_CAP * 8);
  unsigned short* csr = (unsigned short*)alloc((size_t)E * 2);
  unsigned short* hs  = (unsigned short*)alloc((size_t)N * HID_C * 2);
  unsigned short* x2  = (unsigned short*)alloc((size_t)N * HID_C * 2);
  short* w1t         = (short*)alloc((size_t)IN_C * HID_C * 2);
  short* w2t         = (short*)alloc((size_t)HID_C * OUT_C * 2);

  wt_kernel<<<(IN_C * HID_C + 255) / 256, 256, 0, stream>>>(W1, W2, w1t, w2t);
  hipMemsetAsync(ws, 0, zero_bytes, stream);
  phase1_bucket_kernel<<<(E + 255) / 256, 256, 0, stream>>>(
      ei, pairs, bcnt, ovf, ovf_cnt, ovfb, E);
  bucket_scan_kernel<<<1, 256, 0, stream>>>(bcnt, ovfb, bucket_base, rowstart, K, N);
  phase2_csr_kernel<<<K, 256, 0, stream>>>(
      pairs, bcnt, ovf, ovf_cnt, bucket_base, rowstart, dinv, csr, N);

  mfma_gemm_kernel<HID_C, false><<<(NTILES + 3) / 4, 256, 0, stream>>>(
      x, w1t, dinv, hs, NTILES);
  agg_bf16_kernel<HID_C, true, true><<<(N + 15) / 16, 256, 0, stream>>>(
      hs, rowstart, csr, dinv, b1, x2, N);

  mfma_gemm_kernel<OUT_C, true><<<(NTILES + 3) / 4, 256, 0, stream>>>(
      x2, w2t, dinv, hs, NTILES);
  agg_bf16_kernel<OUT_C, false, false><<<(N + 31) / 32, 256, 0, stream>>>(
      hs, rowstart, csr, dinv, b2, out, N);
}

// Round 7
// 153.690 us; speedup vs baseline: 2.3418x; 1.0137x over previous
//
#include <hip/hip_runtime.h>
#include <hip/hip_bf16.h>

// GCN 2-layer forward on MI355X.
// wt+zero -> phase1 (XCD-local bucket scatter) -> bucket_scan -> phase2 (CSR+dinv) ->
// MFMA-GEMM1 (f32 X -> bf16 hs, *dinv) -> agg1 (bf16 in, bf16 out, +b1+relu) ->
// MFMA-GEMM2 (bf16 x2 -> bf16 hs, *dinv) -> agg2 (bf16 in, f32 out, +b2)

#define IN_C 128
#define HID_C 128
#define OUT_C 64
#define BKT_SH 8
#define BKT_NODES 256
#define NSLICE 8
#define CAP 768
#define OVF_CAP 65536

typedef float f32x4 __attribute__((ext_vector_type(4)));
typedef short bf16x8 __attribute__((ext_vector_type(8)));

__device__ inline unsigned short f2bf_rtn(float f) {
  unsigned u = __float_as_uint(f);
  unsigned r = u + 0x7fffu + ((u >> 16) & 1u);
  return (unsigned short)(r >> 16);
}
__device__ inline unsigned pack_bf2(float a, float b) {
  return (unsigned)f2bf_rtn(a) | ((unsigned)f2bf_rtn(b) << 16);
}

// ---- W transpose + bf16 convert + zero the atomic counters (replaces slow memset) ----
__global__ __launch_bounds__(256) void wt_zero_kernel(
    const float* __restrict__ W1, const float* __restrict__ W2,
    short* __restrict__ w1t, short* __restrict__ w2t,
    int* __restrict__ zbase, int zints) {
  int i = blockIdx.x * 256 + threadIdx.x;
  if (i < zints) zbase[i] = 0;
  if (i < IN_C * HID_C) {
    int n = i >> 7, k = i & 127;
    w1t[i] = (short)f2bf_rtn(W1[k * HID_C + n]);
  }
  if (i < HID_C * OUT_C) {
    int n = i >> 7, k = i & 127;
    w2t[i] = (short)f2bf_rtn(W2[k * OUT_C + n]);
  }
}

// ---- CSR build (bucket sort), appends XCD-local via HW_REG_XCC_ID ----
__global__ __launch_bounds__(256) void phase1_bucket_kernel(
    const int* __restrict__ ei, unsigned* __restrict__ pairs,
    int* __restrict__ bcnt, uint2* __restrict__ ovf, int* __restrict__ ovf_cnt,
    int* __restrict__ ovfb, int E) {
  int e = blockIdx.x * 256 + threadIdx.x;
  if (e >= E) return;
  int xcd;
  asm volatile("s_getreg_b32 %0, hwreg(HW_REG_XCC_ID)" : "=s"(xcd));
  int src = ei[e];
  int dst = ei[E + e];
  int b = dst >> BKT_SH;
  int s = xcd & (NSLICE - 1);
  int cell = b * NSLICE + s;
  int pos = atomicAdd(&bcnt[cell * 16], 1);
  unsigned w = (unsigned)src | ((unsigned)(dst & (BKT_NODES - 1)) << 16);
  if (pos < CAP) {
    pairs[(size_t)cell * CAP + pos] = w;
  } else {
    int oi = atomicAdd(ovf_cnt, 1);
    if (oi < OVF_CAP) {
      ovf[oi] = make_uint2((unsigned)src, (unsigned)dst);
      atomicAdd(&ovfb[b], 1);
    }
  }
}

__global__ __launch_bounds__(256) void bucket_scan_kernel(
    const int* __restrict__ bcnt, const int* __restrict__ ovfb,
    int* __restrict__ bucket_base, int* __restrict__ rowstart, int K, int N) {
  int t = threadIdx.x;
  int tot = 0;
  if (t < K) {
    #pragma unroll
    for (int s = 0; s < NSLICE; ++s) {
      int c = bcnt[(t * NSLICE + s) * 16];
      tot += (c < CAP) ? c : CAP;
    }
    tot += ovfb[t];
  }
  int lane = t & 63, wid = t >> 6;
  int inc = tot;
  #pragma unroll
  for (int off = 1; off < 64; off <<= 1) {
    int u = __shfl_up(inc, off, 64);
    if (lane >= off) inc += u;
  }
  __shared__ int ws4[4];
  if (lane == 63) ws4[wid] = inc;
  __syncthreads();
  if (t == 0) {
    int a = ws4[0], b = ws4[1], c = ws4[2];
    ws4[0] = 0; ws4[1] = a; ws4[2] = a + b; ws4[3] = a + b + c;
  }
  __syncthreads();
  int excl = ws4[wid] + inc - tot;
  if (t <= K) bucket_base[t] = excl;
  if (t == K) rowstart[N] = excl;
}

__global__ __launch_bounds__(256) void phase2_csr_kernel(
    const unsigned* __restrict__ pairs, const int* __restrict__ bcnt,
    const uint2* __restrict__ ovf, const int* __restrict__ ovf_cnt,
    const int* __restrict__ bucket_base, int* __restrict__ rowstart,
    float* __restrict__ dinv, unsigned short* __restrict__ csr, int N) {
  int b = blockIdx.x;
  int t = threadIdx.x;
  __shared__ int hist[BKT_NODES];
  __shared__ int cur[BKT_NODES];
  hist[t] = 0;
  __syncthreads();

  int cnts[NSLICE];
  #pragma unroll
  for (int s = 0; s < NSLICE; ++s) {
    int c = bcnt[(b * NSLICE + s) * 16];
    cnts[s] = (c < CAP) ? c : CAP;
  }

  #pragma unroll
  for (int s = 0; s < NSLICE; ++s) {
    const unsigned* reg = pairs + (size_t)(b * NSLICE + s) * CAP;
    for (int i = t; i < cnts[s]; i += 256)
      atomicAdd(&hist[reg[i] >> 16], 1);
  }
  int oc = *ovf_cnt;
  if (oc > OVF_CAP) oc = OVF_CAP;
  for (int i = t; i < oc; i += 256) {
    uint2 p = ovf[i];
    if ((int)(p.y >> BKT_SH) == b) atomicAdd(&hist[p.y & (BKT_NODES - 1)], 1);
  }
  __syncthreads();

  int v = hist[t];
  int lane = t & 63, wid = t >> 6;
  int inc = v;
  #pragma unroll
  for (int off = 1; off < 64; off <<= 1) {
    int u = __shfl_up(inc, off, 64);
    if (lane >= off) inc += u;
  }
  __shared__ int ws4[4];
  if (lane == 63) ws4[wid] = inc;
  __syncthreads();
  if (t == 0) {
    int a = ws4[0], bb = ws4[1], c = ws4[2];
    ws4[0] = 0; ws4[1] = a; ws4[2] = a + bb; ws4[3] = a + bb + c;
  }
  __syncthreads();
  int excl = ws4[wid] + inc - v;

  int base = bucket_base[b];
  int node = b * BKT_NODES + t;
  if (node < N) {
    rowstart[node] = base + excl;
    dinv[node] = rsqrtf((float)(v + 1));
  }
  cur[t] = base + excl;
  __syncthreads();

  #pragma unroll
  for (int s = 0; s < NSLICE; ++s) {
    const unsigned* reg = pairs + (size_t)(b * NSLICE + s) * CAP;
    for (int i = t; i < cnts[s]; i += 256) {
      unsigned w = reg[i];
      int pos = atomicAdd(&cur[w >> 16], 1);
      csr[pos] = (unsigned short)(w & 0xffffu);
    }
  }
  for (int i = t; i < oc; i += 256) {
    uint2 p = ovf[i];
    if ((int)(p.y >> BKT_SH) == b) {
      int pos = atomicAdd(&cur[p.y & (BKT_NODES - 1)], 1);
      csr[pos] = (unsigned short)p.x;
    }
  }
}

// ---- MFMA GEMM: H[r][c] = bf16( (X[r,:] @ W[:,c]) * dinv[r] ) ----
template <int COUT, bool ABF16>
__global__ __launch_bounds__(256) void mfma_gemm_kernel(
    const void* __restrict__ Xv, const short* __restrict__ Wt,
    const float* __restrict__ dinv, unsigned short* __restrict__ H, int ntiles) {
  int lane = threadIdx.x & 63;
  int tile = blockIdx.x * 4 + (threadIdx.x >> 6);
  if (tile >= ntiles) return;
  constexpr int NT = COUT / 16;

  int arow = tile * 16 + (lane & 15);
  int kch = (lane >> 4) * 8;  // 0,8,16,24

  bf16x8 afrag[4];
  if (ABF16) {
    const bf16x8* Xb = (const bf16x8*)Xv;
    #pragma unroll
    for (int kt = 0; kt < 4; ++kt)
      afrag[kt] = Xb[(size_t)arow * 16 + (kt * 32 + kch) / 8];
  } else {
    const float4* Xf = (const float4*)Xv;
    #pragma unroll
    for (int kt = 0; kt < 4; ++kt) {
      float4 f0 = Xf[(size_t)arow * 32 + (kt * 32 + kch) / 4];
      float4 f1 = Xf[(size_t)arow * 32 + (kt * 32 + kch) / 4 + 1];
      bf16x8 a;
      a[0] = (short)f2bf_rtn(f0.x); a[1] = (short)f2bf_rtn(f0.y);
      a[2] = (short)f2bf_rtn(f0.z); a[3] = (short)f2bf_rtn(f0.w);
      a[4] = (short)f2bf_rtn(f1.x); a[5] = (short)f2bf_rtn(f1.y);
      a[6] = (short)f2bf_rtn(f1.z); a[7] = (short)f2bf_rtn(f1.w);
      afrag[kt] = a;
    }
  }

  const bf16x8* W8 = (const bf16x8*)Wt;
  f32x4 zero = {0.f, 0.f, 0.f, 0.f};
  f32x4 acc[NT];
  #pragma unroll
  for (int ct = 0; ct < NT; ++ct) acc[ct] = zero;

  #pragma unroll
  for (int ct = 0; ct < NT; ++ct) {
    int bcol = ct * 16 + (lane & 15);
    #pragma unroll
    for (int kt = 0; kt < 4; ++kt) {
      bf16x8 b = W8[bcol * 16 + (kt * 32 + kch) / 8];
      acc[ct] = __builtin_amdgcn_mfma_f32_16x16x32_bf16(afrag[kt], b, acc[ct], 0, 0, 0);
    }
  }

  int r0 = tile * 16 + (lane >> 4) * 4;
  float di[4];
  #pragma unroll
  for (int j = 0; j < 4; ++j) di[j] = dinv[r0 + j];
  #pragma unroll
  for (int ct = 0; ct < NT; ++ct) {
    #pragma unroll
    for (int j = 0; j < 4; ++j)
      H[(size_t)(r0 + j) * COUT + ct * 16 + (lane & 15)] = f2bf_rtn(acc[ct][j] * di[j]);
  }
}

// ---- pull-agg: out[node,:] = act( dinv[node]*(Hs[node,:]+sum Hs[src,:]) + bias ) ----
template <int C, bool RELU, bool OUT_BF16>
__global__ __launch_bounds__(256) void agg_bf16_kernel(
    const unsigned short* __restrict__ Hs, const int* __restrict__ rowstart,
    const unsigned short* __restrict__ csr, const float* __restrict__ dinv,
    const float* __restrict__ bias, void* __restrict__ out, int n) {
  constexpr int TPN = C / 8;
  constexpr int NPB = 256 / TPN;
  int lane = threadIdx.x % TPN;
  int node = blockIdx.x * NPB + threadIdx.x / TPN;
  if (node >= n) return;

  const uint4* H4 = reinterpret_cast<const uint4*>(Hs);
  int s = rowstart[node];
  int e = rowstart[node + 1];

  float acc[8];
  {
    uint4 v = H4[(size_t)node * TPN + lane];
    acc[0] = __uint_as_float(v.x << 16);
    acc[1] = __uint_as_float(v.x & 0xffff0000u);
    acc[2] = __uint_as_float(v.y << 16);
    acc[3] = __uint_as_float(v.y & 0xffff0000u);
    acc[4] = __uint_as_float(v.z << 16);
    acc[5] = __uint_as_float(v.z & 0xffff0000u);
    acc[6] = __uint_as_float(v.w << 16);
    acc[7] = __uint_as_float(v.w & 0xffff0000u);
  }

  int p = s;
  for (; p + 1 < e; p += 2) {
    int s0 = csr[p];
    int s1 = csr[p + 1];
    uint4 v0 = H4[(size_t)s0 * TPN + lane];
    uint4 v1 = H4[(size_t)s1 * TPN + lane];
    acc[0] += __uint_as_float(v0.x << 16);
    acc[1] += __uint_as_float(v0.x & 0xffff0000u);
    acc[2] += __uint_as_float(v0.y << 16);
    acc[3] += __uint_as_float(v0.y & 0xffff0000u);
    acc[4] += __uint_as_float(v0.z << 16);
    acc[5] += __uint_as_float(v0.z & 0xffff0000u);
    acc[6] += __uint_as_float(v0.w << 16);
    acc[7] += __uint_as_float(v0.w & 0xffff0000u);
    acc[0] += __uint_as_float(v1.x << 16);
    acc[1] += __uint_as_float(v1.x & 0xffff0000u);
    acc[2] += __uint_as_float(v1.y << 16);
    acc[3] += __uint_as_float(v1.y & 0xffff0000u);
    acc[4] += __uint_as_float(v1.z << 16);
    acc[5] += __uint_as_float(v1.z & 0xffff0000u);
    acc[6] += __uint_as_float(v1.w << 16);
    acc[7] += __uint_as_float(v1.w & 0xffff0000u);
  }
  if (p < e) {
    int s0 = csr[p];
    uint4 v0 = H4[(size_t)s0 * TPN + lane];
    acc[0] += __uint_as_float(v0.x << 16);
    acc[1] += __uint_as_float(v0.x & 0xffff0000u);
    acc[2] += __uint_as_float(v0.y << 16);
    acc[3] += __uint_as_float(v0.y & 0xffff0000u);
    acc[4] += __uint_as_float(v0.z << 16);
    acc[5] += __uint_as_float(v0.z & 0xffff0000u);
    acc[6] += __uint_as_float(v0.w << 16);
    acc[7] += __uint_as_float(v0.w & 0xffff0000u);
  }

  float di = dinv[node];
  float4 b0 = reinterpret_cast<const float4*>(bias)[lane * 2];
  float4 b1 = reinterpret_cast<const float4*>(bias)[lane * 2 + 1];
  float r[8];
  r[0] = fmaf(acc[0], di, b0.x);
  r[1] = fmaf(acc[1], di, b0.y);
  r[2] = fmaf(acc[2], di, b0.z);
  r[3] = fmaf(acc[3], di, b0.w);
  r[4] = fmaf(acc[4], di, b1.x);
  r[5] = fmaf(acc[5], di, b1.y);
  r[6] = fmaf(acc[6], di, b1.z);
  r[7] = fmaf(acc[7], di, b1.w);
  if (RELU) {
    #pragma unroll
    for (int j = 0; j < 8; ++j) r[j] = fmaxf(r[j], 0.f);
  }
  if (OUT_BF16) {
    uint4 o;
    o.x = pack_bf2(r[0], r[1]);
    o.y = pack_bf2(r[2], r[3]);
    o.z = pack_bf2(r[4], r[5]);
    o.w = pack_bf2(r[6], r[7]);
    reinterpret_cast<uint4*>(out)[(size_t)node * TPN + lane] = o;
  } else {
    float4* o4 = reinterpret_cast<float4*>(out) + (size_t)node * (C / 4);
    o4[lane * 2] = make_float4(r[0], r[1], r[2], r[3]);
    o4[lane * 2 + 1] = make_float4(r[4], r[5], r[6], r[7]);
  }
}

extern "C" void kernel_launch(void* const* d_in, const int* in_sizes, int n_in,
                              void* d_out, int out_size, void* d_ws, size_t ws_size,
                              hipStream_t stream) {
  const float* x  = (const float*)d_in[0];
  const int*   ei = (const int*)d_in[1];
  const float* W1 = (const float*)d_in[2];
  const float* b1 = (const float*)d_in[3];
  const float* W2 = (const float*)d_in[4];
  const float* b2 = (const float*)d_in[5];
  float* out = (float*)d_out;

  const int N = in_sizes[0] / IN_C;             // 50000
  const int E = in_sizes[1] / 2;                // 800000
  const int K = (N + BKT_NODES - 1) >> BKT_SH;  // 196 buckets
  const int NTILES = (N + 15) / 16;             // 3125 (exact)

  char* ws = (char*)d_ws;
  size_t off = 0;
  auto alloc = [&](size_t bytes) -> void* {
    void* p = ws + off;
    off += (bytes + 255) & ~(size_t)255;
    return p;
  };
  int* bcnt    = (int*)alloc((size_t)K * NSLICE * 16 * 4);
  int* ovf_cnt = (int*)alloc(4);
  int* ovfb    = (int*)alloc((size_t)K * 4);
  size_t zero_bytes = off;
  const int zints = (int)(zero_bytes / 4);

  int*   bucket_base = (int*)  alloc((size_t)(K + 1) * 4);
  int*   rowstart    = (int*)  alloc((size_t)(N + 1) * 4);
  float* dinv        = (float*)alloc((size_t)N * 4);
  unsigned* pairs    = (unsigned*)alloc((size_t)K * NSLICE * CAP * 4);
  uint2* ovf         = (uint2*)alloc((size_t)OVF_CAP * 8);
  unsigned short* csr = (unsigned short*)alloc((size_t)E * 2);
  unsigned short* hs  = (unsigned short*)alloc((size_t)N * HID_C * 2);
  unsigned short* x2  = (unsigned short*)alloc((size_t)N * HID_C * 2);
  short* w1t         = (short*)alloc((size_t)IN_C * HID_C * 2);
  short* w2t         = (short*)alloc((size_t)HID_C * OUT_C * 2);

  int wt_threads = zints > IN_C * HID_C ? zints : IN_C * HID_C;
  wt_zero_kernel<<<(wt_threads + 255) / 256, 256, 0, stream>>>(
      W1, W2, w1t, w2t, (int*)ws, zints);
  phase1_bucket_kernel<<<(E + 255) / 256, 256, 0, stream>>>(
      ei, pairs, bcnt, ovf, ovf_cnt, ovfb, E);
  bucket_scan_kernel<<<1, 256, 0, stream>>>(bcnt, ovfb, bucket_base, rowstart, K, N);
  phase2_csr_kernel<<<K, 256, 0, stream>>>(
      pairs, bcnt, ovf, ovf_cnt, bucket_base, rowstart, dinv, csr, N);

  mfma_gemm_kernel<HID_C, false><<<(NTILES + 3) / 4, 256, 0, stream>>>(
      x, w1t, dinv, hs, NTILES);
  agg_bf16_kernel<HID_C, true, true><<<(N + 15) / 16, 256, 0, stream>>>(
      hs, rowstart, csr, dinv, b1, x2, N);

  mfma_gemm_kernel<OUT_C, true><<<(NTILES + 3) / 4, 256, 0, stream>>>(
      x2, w2t, dinv, hs, NTILES);
  agg_bf16_kernel<OUT_C, false, false><<<(N + 31) / 32, 256, 0, stream>>>(
      hs, rowstart, csr, dinv, b2, out, N);
}

// Round 8
// 123.536 us; speedup vs baseline: 2.9135x; 1.2441x over previous
//
#include <hip/hip_runtime.h>
#include <hip/hip_bf16.h>

// GCN 2-layer forward on MI355X.
// wt+zero -> phase1 (LDS-binned bucket partition, dense runs) -> bucket_scan ->
// phase2 (per-bucket LDS hist/scan -> rowstart+dinv+csr) ->
// MFMA-GEMM1 (f32 X -> bf16 hs, *dinv) -> agg1 (bf16 in, bf16 out, +b1+relu) ->
// MFMA-GEMM2 (bf16 x2 -> bf16 hs, *dinv) -> agg2 (bf16 in, f32 out, +b2)

#define IN_C 128
#define HID_C 128
#define OUT_C 64
#define BKT_SH 8
#define BKT_NODES 256
#define CHUNK 4096               // edges per phase1 block
#define CAPB 6144                // per-bucket region capacity (mean 4081, +32 sigma)
#define OVF_CAP 65536

typedef float f32x4 __attribute__((ext_vector_type(4)));
typedef short bf16x8 __attribute__((ext_vector_type(8)));

__device__ inline unsigned short f2bf_rtn(float f) {
  unsigned u = __float_as_uint(f);
  unsigned r = u + 0x7fffu + ((u >> 16) & 1u);
  return (unsigned short)(r >> 16);
}
__device__ inline unsigned pack_bf2(float a, float b) {
  return (unsigned)f2bf_rtn(a) | ((unsigned)f2bf_rtn(b) << 16);
}

// ---- W transpose + bf16 convert + zero the atomic counters ----
__global__ __launch_bounds__(256) void wt_zero_kernel(
    const float* __restrict__ W1, const float* __restrict__ W2,
    short* __restrict__ w1t, short* __restrict__ w2t,
    int* __restrict__ zbase, int zints) {
  int i = blockIdx.x * 256 + threadIdx.x;
  if (i < zints) zbase[i] = 0;
  if (i < IN_C * HID_C) {
    int n = i >> 7, k = i & 127;
    w1t[i] = (short)f2bf_rtn(W1[k * HID_C + n]);
  }
  if (i < HID_C * OUT_C) {
    int n = i >> 7, k = i & 127;
    w2t[i] = (short)f2bf_rtn(W2[k * OUT_C + n]);
  }
}

// ---- Phase 1: LDS-binned partition. Each block bins a CHUNK of edges by
// bucket (dst>>8) in LDS, then writes dense per-bucket runs to global.
// Word layout: src(16) | dst_local(8) | bucket(8).
__global__ __launch_bounds__(256) void phase1_bin_kernel(
    const int* __restrict__ ei, unsigned* __restrict__ pairs,
    int* __restrict__ bcnt, uint2* __restrict__ ovf, int* __restrict__ ovf_cnt,
    int* __restrict__ ovfb, int E, int K) {
  __shared__ unsigned buf[CHUNK];
  __shared__ int hist[256];
  __shared__ int lofs[256];
  __shared__ int cur[256];
  __shared__ int gbase[256];
  int t = threadIdx.x;
  int base_e = blockIdx.x * CHUNK;
  int cnt_e = E - base_e;
  if (cnt_e > CHUNK) cnt_e = CHUNK;

  hist[t] = 0;
  __syncthreads();

  // pass 1: count
  for (int i = t; i < cnt_e; i += 256)
    atomicAdd(&hist[ei[E + base_e + i] >> BKT_SH], 1);
  __syncthreads();

  // exclusive scan of hist[256]
  int v = hist[t];
  int lane = t & 63, wid = t >> 6;
  int inc = v;
  #pragma unroll
  for (int off = 1; off < 64; off <<= 1) {
    int u = __shfl_up(inc, off, 64);
    if (lane >= off) inc += u;
  }
  __shared__ int ws4[4];
  if (lane == 63) ws4[wid] = inc;
  __syncthreads();
  if (t == 0) {
    int a = ws4[0], b = ws4[1], c = ws4[2];
    ws4[0] = 0; ws4[1] = a; ws4[2] = a + b; ws4[3] = a + b + c;
  }
  __syncthreads();
  int excl = ws4[wid] + inc - v;
  lofs[t] = excl;
  cur[t] = excl;
  if (t < K && v > 0) gbase[t] = atomicAdd(&bcnt[t], v);
  __syncthreads();

  // pass 2: scatter into LDS, bucket-major
  for (int i = t; i < cnt_e; i += 256) {
    int src = ei[base_e + i];
    int dst = ei[E + base_e + i];
    int b = dst >> BKT_SH;
    int pos = atomicAdd(&cur[b], 1);
    buf[pos] = (unsigned)src | ((unsigned)(dst & (BKT_NODES - 1)) << 16) |
               ((unsigned)b << 24);
  }
  __syncthreads();

  // copy out: consecutive LDS slots within a run -> consecutive global addrs
  for (int i = t; i < cnt_e; i += 256) {
    unsigned w = buf[i];
    int b = w >> 24;
    int g = gbase[b] + (i - lofs[b]);
    if (g < CAPB) {
      pairs[(size_t)b * CAPB + g] = w;
    } else {
      int oi = atomicAdd(ovf_cnt, 1);
      if (oi < OVF_CAP) {
        unsigned dst = (unsigned)(b << BKT_SH) | ((w >> 16) & 0xFFu);
        ovf[oi] = make_uint2(w & 0xFFFFu, dst);
        atomicAdd(&ovfb[b], 1);
      }
    }
  }
}

__global__ __launch_bounds__(256) void bucket_scan_kernel(
    const int* __restrict__ bcnt, const int* __restrict__ ovfb,
    int* __restrict__ bucket_base, int* __restrict__ rowstart, int K, int N) {
  int t = threadIdx.x;
  int tot = 0;
  if (t < K) {
    int c = bcnt[t];
    tot = (c < CAPB ? c : CAPB) + ovfb[t];
  }
  int lane = t & 63, wid = t >> 6;
  int inc = tot;
  #pragma unroll
  for (int off = 1; off < 64; off <<= 1) {
    int u = __shfl_up(inc, off, 64);
    if (lane >= off) inc += u;
  }
  __shared__ int ws4[4];
  if (lane == 63) ws4[wid] = inc;
  __syncthreads();
  if (t == 0) {
    int a = ws4[0], b = ws4[1], c = ws4[2];
    ws4[0] = 0; ws4[1] = a; ws4[2] = a + b; ws4[3] = a + b + c;
  }
  __syncthreads();
  int excl = ws4[wid] + inc - tot;
  if (t <= K) bucket_base[t] = excl;
  if (t == K) rowstart[N] = excl;
}

__global__ __launch_bounds__(256) void phase2_csr_kernel(
    const unsigned* __restrict__ pairs, const int* __restrict__ bcnt,
    const uint2* __restrict__ ovf, const int* __restrict__ ovf_cnt,
    const int* __restrict__ bucket_base, int* __restrict__ rowstart,
    float* __restrict__ dinv, unsigned short* __restrict__ csr, int N) {
  int b = blockIdx.x;
  int t = threadIdx.x;
  __shared__ int hist[BKT_NODES];
  __shared__ int cur[BKT_NODES];
  hist[t] = 0;
  __syncthreads();

  int cnt = bcnt[b];
  if (cnt > CAPB) cnt = CAPB;
  const unsigned* reg = pairs + (size_t)b * CAPB;

  for (int i = t; i < cnt; i += 256)
    atomicAdd(&hist[(reg[i] >> 16) & 0xFFu], 1);
  int oc = *ovf_cnt;
  if (oc > OVF_CAP) oc = OVF_CAP;
  for (int i = t; i < oc; i += 256) {
    uint2 p = ovf[i];
    if ((int)(p.y >> BKT_SH) == b) atomicAdd(&hist[p.y & (BKT_NODES - 1)], 1);
  }
  __syncthreads();

  int v = hist[t];
  int lane = t & 63, wid = t >> 6;
  int inc = v;
  #pragma unroll
  for (int off = 1; off < 64; off <<= 1) {
    int u = __shfl_up(inc, off, 64);
    if (lane >= off) inc += u;
  }
  __shared__ int ws4[4];
  if (lane == 63) ws4[wid] = inc;
  __syncthreads();
  if (t == 0) {
    int a = ws4[0], bb = ws4[1], c = ws4[2];
    ws4[0] = 0; ws4[1] = a; ws4[2] = a + bb; ws4[3] = a + bb + c;
  }
  __syncthreads();
  int excl = ws4[wid] + inc - v;

  int base = bucket_base[b];
  int node = b * BKT_NODES + t;
  if (node < N) {
    rowstart[node] = base + excl;
    dinv[node] = rsqrtf((float)(v + 1));
  }
  cur[t] = base + excl;
  __syncthreads();

  for (int i = t; i < cnt; i += 256) {
    unsigned w = reg[i];
    int pos = atomicAdd(&cur[(w >> 16) & 0xFFu], 1);
    csr[pos] = (unsigned short)(w & 0xffffu);
  }
  for (int i = t; i < oc; i += 256) {
    uint2 p = ovf[i];
    if ((int)(p.y >> BKT_SH) == b) {
      int pos = atomicAdd(&cur[p.y & (BKT_NODES - 1)], 1);
      csr[pos] = (unsigned short)p.x;
    }
  }
}

// ---- MFMA GEMM: H[r][c] = bf16( (X[r,:] @ W[:,c]) * dinv[r] ) ----
template <int COUT, bool ABF16>
__global__ __launch_bounds__(256) void mfma_gemm_kernel(
    const void* __restrict__ Xv, const short* __restrict__ Wt,
    const float* __restrict__ dinv, unsigned short* __restrict__ H, int ntiles) {
  int lane = threadIdx.x & 63;
  int tile = blockIdx.x * 4 + (threadIdx.x >> 6);
  if (tile >= ntiles) return;
  constexpr int NT = COUT / 16;

  int arow = tile * 16 + (lane & 15);
  int kch = (lane >> 4) * 8;  // 0,8,16,24

  bf16x8 afrag[4];
  if (ABF16) {
    const bf16x8* Xb = (const bf16x8*)Xv;
    #pragma unroll
    for (int kt = 0; kt < 4; ++kt)
      afrag[kt] = Xb[(size_t)arow * 16 + (kt * 32 + kch) / 8];
  } else {
    const float4* Xf = (const float4*)Xv;
    #pragma unroll
    for (int kt = 0; kt < 4; ++kt) {
      float4 f0 = Xf[(size_t)arow * 32 + (kt * 32 + kch) / 4];
      float4 f1 = Xf[(size_t)arow * 32 + (kt * 32 + kch) / 4 + 1];
      bf16x8 a;
      a[0] = (short)f2bf_rtn(f0.x); a[1] = (short)f2bf_rtn(f0.y);
      a[2] = (short)f2bf_rtn(f0.z); a[3] = (short)f2bf_rtn(f0.w);
      a[4] = (short)f2bf_rtn(f1.x); a[5] = (short)f2bf_rtn(f1.y);
      a[6] = (short)f2bf_rtn(f1.z); a[7] = (short)f2bf_rtn(f1.w);
      afrag[kt] = a;
    }
  }

  const bf16x8* W8 = (const bf16x8*)Wt;
  f32x4 zero = {0.f, 0.f, 0.f, 0.f};
  f32x4 acc[NT];
  #pragma unroll
  for (int ct = 0; ct < NT; ++ct) acc[ct] = zero;

  #pragma unroll
  for (int ct = 0; ct < NT; ++ct) {
    int bcol = ct * 16 + (lane & 15);
    #pragma unroll
    for (int kt = 0; kt < 4; ++kt) {
      bf16x8 b = W8[bcol * 16 + (kt * 32 + kch) / 8];
      acc[ct] = __builtin_amdgcn_mfma_f32_16x16x32_bf16(afrag[kt], b, acc[ct], 0, 0, 0);
    }
  }

  int r0 = tile * 16 + (lane >> 4) * 4;
  float di[4];
  #pragma unroll
  for (int j = 0; j < 4; ++j) di[j] = dinv[r0 + j];
  #pragma unroll
  for (int ct = 0; ct < NT; ++ct) {
    #pragma unroll
    for (int j = 0; j < 4; ++j)
      H[(size_t)(r0 + j) * COUT + ct * 16 + (lane & 15)] = f2bf_rtn(acc[ct][j] * di[j]);
  }
}

// ---- pull-agg: out[node,:] = act( dinv[node]*(Hs[node,:]+sum Hs[src,:]) + bias ) ----
template <int C, bool RELU, bool OUT_BF16>
__global__ __launch_bounds__(256) void agg_bf16_kernel(
    const unsigned short* __restrict__ Hs, const int* __restrict__ rowstart,
    const unsigned short* __restrict__ csr, const float* __restrict__ dinv,
    const float* __restrict__ bias, void* __restrict__ out, int n) {
  constexpr int TPN = C / 8;
  constexpr int NPB = 256 / TPN;
  int lane = threadIdx.x % TPN;
  int node = blockIdx.x * NPB + threadIdx.x / TPN;
  if (node >= n) return;

  const uint4* H4 = reinterpret_cast<const uint4*>(Hs);
  int s = rowstart[node];
  int e = rowstart[node + 1];

  float acc[8];
  {
    uint4 v = H4[(size_t)node * TPN + lane];
    acc[0] = __uint_as_float(v.x << 16);
    acc[1] = __uint_as_float(v.x & 0xffff0000u);
    acc[2] = __uint_as_float(v.y << 16);
    acc[3] = __uint_as_float(v.y & 0xffff0000u);
    acc[4] = __uint_as_float(v.z << 16);
    acc[5] = __uint_as_float(v.z & 0xffff0000u);
    acc[6] = __uint_as_float(v.w << 16);
    acc[7] = __uint_as_float(v.w & 0xffff0000u);
  }

  int p = s;
  for (; p + 1 < e; p += 2) {
    int s0 = csr[p];
    int s1 = csr[p + 1];
    uint4 v0 = H4[(size_t)s0 * TPN + lane];
    uint4 v1 = H4[(size_t)s1 * TPN + lane];
    acc[0] += __uint_as_float(v0.x << 16);
    acc[1] += __uint_as_float(v0.x & 0xffff0000u);
    acc[2] += __uint_as_float(v0.y << 16);
    acc[3] += __uint_as_float(v0.y & 0xffff0000u);
    acc[4] += __uint_as_float(v0.z << 16);
    acc[5] += __uint_as_float(v0.z & 0xffff0000u);
    acc[6] += __uint_as_float(v0.w << 16);
    acc[7] += __uint_as_float(v0.w & 0xffff0000u);
    acc[0] += __uint_as_float(v1.x << 16);
    acc[1] += __uint_as_float(v1.x & 0xffff0000u);
    acc[2] += __uint_as_float(v1.y << 16);
    acc[3] += __uint_as_float(v1.y & 0xffff0000u);
    acc[4] += __uint_as_float(v1.z << 16);
    acc[5] += __uint_as_float(v1.z & 0xffff0000u);
    acc[6] += __uint_as_float(v1.w << 16);
    acc[7] += __uint_as_float(v1.w & 0xffff0000u);
  }
  if (p < e) {
    int s0 = csr[p];
    uint4 v0 = H4[(size_t)s0 * TPN + lane];
    acc[0] += __uint_as_float(v0.x << 16);
    acc[1] += __uint_as_float(v0.x & 0xffff0000u);
    acc[2] += __uint_as_float(v0.y << 16);
    acc[3] += __uint_as_float(v0.y & 0xffff0000u);
    acc[4] += __uint_as_float(v0.z << 16);
    acc[5] += __uint_as_float(v0.z & 0xffff0000u);
    acc[6] += __uint_as_float(v0.w << 16);
    acc[7] += __uint_as_float(v0.w & 0xffff0000u);
  }

  float di = dinv[node];
  float4 b0 = reinterpret_cast<const float4*>(bias)[lane * 2];
  float4 b1 = reinterpret_cast<const float4*>(bias)[lane * 2 + 1];
  float r[8];
  r[0] = fmaf(acc[0], di, b0.x);
  r[1] = fmaf(acc[1], di, b0.y);
  r[2] = fmaf(acc[2], di, b0.z);
  r[3] = fmaf(acc[3], di, b0.w);
  r[4] = fmaf(acc[4], di, b1.x);
  r[5] = fmaf(acc[5], di, b1.y);
  r[6] = fmaf(acc[6], di, b1.z);
  r[7] = fmaf(acc[7], di, b1.w);
  if (RELU) {
    #pragma unroll
    for (int j = 0; j < 8; ++j) r[j] = fmaxf(r[j], 0.f);
  }
  if (OUT_BF16) {
    uint4 o;
    o.x = pack_bf2(r[0], r[1]);
    o.y = pack_bf2(r[2], r[3]);
    o.z = pack_bf2(r[4], r[5]);
    o.w = pack_bf2(r[6], r[7]);
    reinterpret_cast<uint4*>(out)[(size_t)node * TPN + lane] = o;
  } else {
    float4* o4 = reinterpret_cast<float4*>(out) + (size_t)node * (C / 4);
    o4[lane * 2] = make_float4(r[0], r[1], r[2], r[3]);
    o4[lane * 2 + 1] = make_float4(r[4], r[5], r[6], r[7]);
  }
}

extern "C" void kernel_launch(void* const* d_in, const int* in_sizes, int n_in,
                              void* d_out, int out_size, void* d_ws, size_t ws_size,
                              hipStream_t stream) {
  const float* x  = (const float*)d_in[0];
  const int*   ei = (const int*)d_in[1];
  const float* W1 = (const float*)d_in[2];
  const float* b1 = (const float*)d_in[3];
  const float* W2 = (const float*)d_in[4];
  const float* b2 = (const float*)d_in[5];
  float* out = (float*)d_out;

  const int N = in_sizes[0] / IN_C;             // 50000
  const int E = in_sizes[1] / 2;                // 800000
  const int K = (N + BKT_NODES - 1) >> BKT_SH;  // 196 buckets
  const int NTILES = (N + 15) / 16;             // 3125 (exact)

  char* ws = (char*)d_ws;
  size_t off = 0;
  auto alloc = [&](size_t bytes) -> void* {
    void* p = ws + off;
    off += (bytes + 255) & ~(size_t)255;
    return p;
  };
  int* bcnt    = (int*)alloc((size_t)K * 4);
  int* ovf_cnt = (int*)alloc(4);
  int* ovfb    = (int*)alloc((size_t)K * 4);
  size_t zero_bytes = off;
  const int zints = (int)(zero_bytes / 4);

  int*   bucket_base = (int*)  alloc((size_t)(K + 1) * 4);
  int*   rowstart    = (int*)  alloc((size_t)(N + 1) * 4);
  float* dinv        = (float*)alloc((size_t)N * 4);
  unsigned* pairs    = (unsigned*)alloc((size_t)K * CAPB * 4);
  uint2* ovf         = (uint2*)alloc((size_t)OVF_CAP * 8);
  unsigned short* csr = (unsigned short*)alloc((size_t)E * 2);
  unsigned short* hs  = (unsigned short*)alloc((size_t)N * HID_C * 2);
  unsigned short* x2  = (unsigned short*)alloc((size_t)N * HID_C * 2);
  short* w1t         = (short*)alloc((size_t)IN_C * HID_C * 2);
  short* w2t         = (short*)alloc((size_t)HID_C * OUT_C * 2);

  int wt_threads = zints > IN_C * HID_C ? zints : IN_C * HID_C;
  wt_zero_kernel<<<(wt_threads + 255) / 256, 256, 0, stream>>>(
      W1, W2, w1t, w2t, (int*)ws, zints);
  phase1_bin_kernel<<<(E + CHUNK - 1) / CHUNK, 256, 0, stream>>>(
      ei, pairs, bcnt, ovf, ovf_cnt, ovfb, E, K);
  bucket_scan_kernel<<<1, 256, 0, stream>>>(bcnt, ovfb, bucket_base, rowstart, K, N);
  phase2_csr_kernel<<<K, 256, 0, stream>>>(
      pairs, bcnt, ovf, ovf_cnt, bucket_base, rowstart, dinv, csr, N);

  mfma_gemm_kernel<HID_C, false><<<(NTILES + 3) / 4, 256, 0, stream>>>(
      x, w1t, dinv, hs, NTILES);
  agg_bf16_kernel<HID_C, true, true><<<(N + 15) / 16, 256, 0, stream>>>(
      hs, rowstart, csr, dinv, b1, x2, N);

  mfma_gemm_kernel<OUT_C, true><<<(NTILES + 3) / 4, 256, 0, stream>>>(
      x2, w2t, dinv, hs, NTILES);
  agg_bf16_kernel<OUT_C, false, false><<<(N + 31) / 32, 256, 0, stream>>>(
      hs, rowstart, csr, dinv, b2, out, N);
}